// Round 1
// baseline (586.922 us; speedup 1.0000x reference)
//
#include <hip/hip_runtime.h>

#define NB 288          // 32 query + 256 poi batches
#define NBQ 32
#define NBP 256
#define LTOK 16
#define CIN 8192
#define H1 256
#define H2 32
#define MASKW 256       // 8192 bits / 32

__device__ __forceinline__ float block_reduce_sum_256(float v, float* red) {
    int tid = threadIdx.x;
    red[tid] = v; __syncthreads();
    for (int st = 128; st > 0; st >>= 1) {
        if (tid < st) red[tid] += red[tid + st];
        __syncthreads();
    }
    float r = red[0];
    __syncthreads();
    return r;
}

// enc_w (256, 8192) -> enc_wT (8192, 256)
__global__ __launch_bounds__(256) void k_transpose(const float* __restrict__ w,
                                                   float* __restrict__ wt) {
    __shared__ float tile[32][33];
    int k0 = blockIdx.x * 32;          // along 8192
    int h0 = blockIdx.y * 32;          // along 256
    int tx = threadIdx.x & 31, ty = threadIdx.x >> 5;   // ty 0..7
#pragma unroll
    for (int i = 0; i < 32; i += 8)
        tile[ty + i][tx] = w[(h0 + ty + i) * CIN + k0 + tx];
    __syncthreads();
#pragma unroll
    for (int i = 0; i < 32; i += 8)
        wt[(size_t)(k0 + ty + i) * H1 + h0 + tx] = tile[tx][ty + i];
}

// One block per (batch,token) row: sparse encode + packed bloom
__global__ __launch_bounds__(256) void k_encode(const float* __restrict__ qx,
                                                const float* __restrict__ px,
                                                const float* __restrict__ wt,
                                                float* __restrict__ encoded,
                                                unsigned* __restrict__ masks) {
    int row = blockIdx.x;              // 0..4607
    int b = row >> 4;
    const float* x = (b < NBQ) ? (qx + (size_t)row * CIN)
                               : (px + (size_t)(row - NBQ * LTOK) * CIN);
    __shared__ int idxs[2048];
    __shared__ int cnt;
    int tid = threadIdx.x;
    if (tid == 0) cnt = 0;
    __syncthreads();
    const float4* x4 = (const float4*)x;
#pragma unroll
    for (int j = 0; j < 8; ++j) {
        float4 v = x4[j * 256 + tid];
        int base = (j * 256 + tid) * 4;
        float vv[4] = {v.x, v.y, v.z, v.w};
#pragma unroll
        for (int c = 0; c < 4; ++c) {
            if (vv[c] != 0.f) {
                int k = base + c;
                int p = atomicAdd(&cnt, 1);
                if (p < 2048) idxs[p] = k;
                atomicOr(&masks[b * MASKW + (k >> 5)], 1u << (k & 31));
            }
        }
    }
    __syncthreads();
    int n = min(cnt, 2048);
    float acc = 0.f;
#pragma unroll 4
    for (int j = 0; j < n; ++j)
        acc += wt[(size_t)idxs[j] * H1 + tid];
    encoded[(size_t)row * H1 + tid] = acc;
}

__global__ __launch_bounds__(256) void k_qbits(const unsigned* __restrict__ masks,
                                               float* __restrict__ qbits) {
    __shared__ int red[256];
    int q = blockIdx.x, tid = threadIdx.x;
    red[tid] = __popc(masks[q * MASKW + tid]);
    __syncthreads();
    for (int st = 128; st > 0; st >>= 1) {
        if (tid < st) red[tid] += red[tid + st];
        __syncthreads();
    }
    if (tid == 0) qbits[q] = (float)red[0];
}

// One block per batch: 3-layer conv block in LDS + residual + mean over tokens
__global__ __launch_bounds__(256) void k_conv(const float* __restrict__ encoded,
                                              const float* __restrict__ w1, const float* __restrict__ b1,
                                              const float* __restrict__ w2, const float* __restrict__ b2,
                                              const float* __restrict__ w3, const float* __restrict__ b3,
                                              float* __restrict__ emb) {
    int b = blockIdx.x;
    __shared__ float buf0[256][20];    // [channel][t+2], pad t'=0,1,18,19
    __shared__ float buf1[256][20];
    int tid = threadIdx.x;
    buf0[tid][0] = 0.f; buf0[tid][1] = 0.f; buf0[tid][18] = 0.f; buf0[tid][19] = 0.f;
    buf1[tid][0] = 0.f; buf1[tid][1] = 0.f; buf1[tid][18] = 0.f; buf1[tid][19] = 0.f;
    float xsum = 0.f;
#pragma unroll
    for (int t = 0; t < 16; ++t) {
        float v = encoded[(size_t)(b * 16 + t) * 256 + tid];   // coalesced
        buf0[tid][t + 2] = v;
        xsum += v;
    }
    __syncthreads();
    float* cur = &buf0[0][0];
    float* nxt = &buf1[0][0];
    const float* ws_[3] = {w1, w2, w3};
    const float* bs_[3] = {b1, b2, b3};
    float acc[16];
#pragma unroll
    for (int layer = 0; layer < 3; ++layer) {
        const float* wrow = ws_[layer] + (size_t)tid * 1280;   // w[o][i][dt]
#pragma unroll
        for (int t = 0; t < 16; ++t) acc[t] = 0.f;
#pragma unroll 2
        for (int i = 0; i < 256; ++i) {
            float xv[20];
#pragma unroll
            for (int u = 0; u < 5; ++u)
                *(float4*)&xv[u * 4] = *(const float4*)&cur[i * 20 + u * 4];  // LDS broadcast
            float wv[5];
#pragma unroll
            for (int d = 0; d < 5; ++d) wv[d] = wrow[i * 5 + d];
#pragma unroll
            for (int d = 0; d < 5; ++d)
#pragma unroll
                for (int t = 0; t < 16; ++t)
                    acc[t] = fmaf(wv[d], xv[t + d], acc[t]);
        }
        float bias = bs_[layer][tid];
#pragma unroll
        for (int t = 0; t < 16; ++t)
            nxt[tid * 20 + t + 2] = fmaxf(acc[t] + bias, 0.f);
        __syncthreads();
        float* tmp = cur; cur = nxt; nxt = tmp;
    }
    float s = xsum;                    // residual: mean(conv_out + x)
#pragma unroll
    for (int t = 0; t < 16; ++t) s += cur[tid * 20 + t + 2];
    emb[b * 256 + tid] = s * (1.f / 16.f);
}

// Cmat[b][o] = sum_i dec_w1[o][i + (b<32?0:256)] * relu(emb[b][i])
__global__ __launch_bounds__(256) void k_ab(const float* __restrict__ emb,
                                            const float* __restrict__ w1,
                                            float* __restrict__ Cmat) {
    int b = blockIdx.x, tid = threadIdx.x;
    __shared__ float e[256];
    __shared__ float red[256];
    e[tid] = fmaxf(emb[b * 256 + tid], 0.f);
    __syncthreads();
    int o = tid & 31, seg = tid >> 5;  // 32 outputs x 8 segments
    const float* wr = w1 + (size_t)o * 512 + (b < NBQ ? 0 : 256) + seg * 32;
    float s = 0.f;
#pragma unroll
    for (int i = 0; i < 32; ++i) s = fmaf(wr[i], e[seg * 32 + i], s);
    red[tid] = s; __syncthreads();
    if (tid < 128) red[tid] += red[tid + 128]; __syncthreads();
    if (tid < 64)  red[tid] += red[tid + 64];  __syncthreads();
    if (tid < 32) {
        red[tid] += red[tid + 32];
        Cmat[b * 32 + tid] = red[tid];
    }
}

// One block per (q,p) pair: tiny MLP + sparse masked decode
__global__ __launch_bounds__(256) void k_pair(const float* __restrict__ Cmat,
                                              const float* __restrict__ b1,
                                              const float* __restrict__ w2,
                                              const float* __restrict__ b2,
                                              const float* __restrict__ w3,
                                              const unsigned* __restrict__ masks,
                                              const float* __restrict__ qbits,
                                              float* __restrict__ desc) {
    int p = blockIdx.x, q = blockIdx.y;
    __shared__ float h1[32], h2[32];
    __shared__ float red[256];
    int tid = threadIdx.x;
    if (tid < 32)
        h1[tid] = fmaxf(Cmat[q * 32 + tid] + Cmat[(NBQ + p) * 32 + tid] + b1[tid], 0.f);
    __syncthreads();
    if (tid < 32) {
        float s = b2[tid];
#pragma unroll
        for (int j = 0; j < 32; ++j) s = fmaf(w2[tid * 32 + j], h1[j], s);
        h2[tid] = fmaxf(s, 0.f);
    }
    __syncthreads();
    float h2r[32];
#pragma unroll
    for (int j = 0; j < 32; ++j) h2r[j] = h2[j];
    unsigned m = masks[q * MASKW + tid] & masks[(NBQ + p) * MASKW + tid];
    float local = 0.f;
    while (m) {
        int bit = __ffs(m) - 1;
        m &= m - 1;
        int k = tid * 32 + bit;
        const float* r = w3 + (size_t)k * 32;
        float dot = 0.f;
#pragma unroll
        for (int j = 0; j < 32; ++j) dot = fmaf(h2r[j], r[j], dot);
        local += 1.f + (dot >= 0.f ? dot : dot * 0.125f);   // leaky(1/8) + 1
    }
    float total = block_reduce_sum_256(local, red);
    if (tid == 0) desc[q * 256 + p] = total / qbits[q];
}

// One block per q row: normalize over p, fuse geo distance
__global__ __launch_bounds__(256) void k_final(const float* __restrict__ desc,
                                               const float* __restrict__ qloc,
                                               const float* __restrict__ ploc,
                                               const float* __restrict__ sa,
                                               const float* __restrict__ sb,
                                               const float* __restrict__ sc,
                                               const float* __restrict__ sd,
                                               float* __restrict__ out) {
    __shared__ float red[256];
    int q = blockIdx.x, tid = threadIdx.x;
    float v = desc[q * 256 + tid];
    float mean = block_reduce_sum_256(v, red) * (1.f / 256.f);
    float dv = v - mean;
    float var = block_reduce_sum_256(dv * dv, red) * (1.f / 255.f);   // ddof=1
    float norm = dv / (sqrtf(var) + 1e-6f);
    float dx = qloc[q * 2]     - ploc[tid * 2];
    float dy = qloc[q * 2 + 1] - ploc[tid * 2 + 1];
    float dist = sqrtf(dx * dx + dy * dy);
    float z = sa[0] * norm + sb[0];
    float sig = 1.f / (1.f + expf(-z));
    out[q * 256 + tid] = (sc[0] - sig) * (-logf(dist + 1.f) - sd[0]);
}

extern "C" void kernel_launch(void* const* d_in, const int* in_sizes, int n_in,
                              void* d_out, int out_size, void* d_ws, size_t ws_size,
                              hipStream_t stream) {
    const float* qx   = (const float*)d_in[0];
    const float* qloc = (const float*)d_in[1];
    const float* px   = (const float*)d_in[2];
    const float* ploc = (const float*)d_in[3];
    const float* encw = (const float*)d_in[4];
    const float* cw1  = (const float*)d_in[5];
    const float* cb1  = (const float*)d_in[6];
    const float* cw2  = (const float*)d_in[7];
    const float* cb2  = (const float*)d_in[8];
    const float* cw3  = (const float*)d_in[9];
    const float* cb3  = (const float*)d_in[10];
    const float* dw1  = (const float*)d_in[11];
    const float* db1  = (const float*)d_in[12];
    const float* dw2  = (const float*)d_in[13];
    const float* db2  = (const float*)d_in[14];
    const float* dw3  = (const float*)d_in[15];
    const float* sa   = (const float*)d_in[16];
    const float* sb   = (const float*)d_in[17];
    const float* sc   = (const float*)d_in[18];
    const float* sd   = (const float*)d_in[19];

    char* w = (char*)d_ws;
    float*    enc_wT  = (float*)w;    w += (size_t)CIN * H1 * 4;        // 8 MB
    float*    encoded = (float*)w;    w += (size_t)NB * LTOK * H1 * 4;  // 4.5 MB
    float*    emb     = (float*)w;    w += (size_t)NB * H1 * 4;
    float*    Cmat    = (float*)w;    w += (size_t)NB * H2 * 4;
    unsigned* masks   = (unsigned*)w; w += (size_t)NB * MASKW * 4;
    float*    qbits   = (float*)w;    w += 256;                          // 32 floats, padded
    float*    desc    = (float*)w;    w += (size_t)NBQ * NBP * 4;

    hipMemsetAsync(masks, 0, (size_t)NB * MASKW * 4, stream);
    k_transpose<<<dim3(CIN / 32, H1 / 32), 256, 0, stream>>>(encw, enc_wT);
    k_encode<<<NB * LTOK, 256, 0, stream>>>(qx, px, enc_wT, encoded, masks);
    k_qbits<<<NBQ, 256, 0, stream>>>(masks, qbits);
    k_conv<<<NB, 256, 0, stream>>>(encoded, cw1, cb1, cw2, cb2, cw3, cb3, emb);
    k_ab<<<NB, 256, 0, stream>>>(emb, dw1, Cmat);
    k_pair<<<dim3(NBP, NBQ), 256, 0, stream>>>(Cmat, db1, dw2, db2, dw3, masks, qbits, desc);
    k_final<<<NBQ, 256, 0, stream>>>(desc, qloc, ploc, sa, sb, sc, sd, (float*)d_out);
}

// Round 2
// 439.314 us; speedup vs baseline: 1.3360x; 1.3360x over previous
//
#include <hip/hip_runtime.h>

#define NB 288          // 32 query + 256 poi batches
#define NBQ 32
#define NBP 256
#define LTOK 16
#define CIN 8192
#define H1 256
#define H2 32
#define MASKW 256       // 8192 bits / 32
#define XROW 264        // padded LDS row stride (bf16 elements) -> conflict-free A-frag reads
#define XBUFN (20 * XROW)  // shorts per activation buffer (20 padded token rows)

typedef __attribute__((ext_vector_type(8))) short short8;   // 8 bf16 = 4 VGPRs
typedef __attribute__((ext_vector_type(4))) float f32x4;

__device__ __forceinline__ unsigned short f2bf(float f) {
    unsigned u = __float_as_uint(f);
    u += 0x7fffu + ((u >> 16) & 1u);
    return (unsigned short)(u >> 16);
}

__device__ __forceinline__ float block_reduce_sum_256(float v, float* red) {
    int tid = threadIdx.x;
    red[tid] = v; __syncthreads();
    for (int st = 128; st > 0; st >>= 1) {
        if (tid < st) red[tid] += red[tid + st];
        __syncthreads();
    }
    float r = red[0];
    __syncthreads();
    return r;
}

// enc_w (256, 8192) -> enc_wT (8192, 256) fp32
__global__ __launch_bounds__(256) void k_transpose(const float* __restrict__ w,
                                                   float* __restrict__ wt) {
    __shared__ float tile[32][33];
    int k0 = blockIdx.x * 32;
    int h0 = blockIdx.y * 32;
    int tx = threadIdx.x & 31, ty = threadIdx.x >> 5;
#pragma unroll
    for (int i = 0; i < 32; i += 8)
        tile[ty + i][tx] = w[(h0 + ty + i) * CIN + k0 + tx];
    __syncthreads();
#pragma unroll
    for (int i = 0; i < 32; i += 8)
        wt[(size_t)(k0 + ty + i) * H1 + h0 + tx] = tile[tx][ty + i];
}

// conv weights w[o][i][d] fp32 -> WT bf16 [o][d][i], 3 layers
__global__ __launch_bounds__(256) void k_wprep(const float* __restrict__ w1,
                                               const float* __restrict__ w2,
                                               const float* __restrict__ w3,
                                               unsigned short* __restrict__ wtb) {
    int bx = blockIdx.x;                 // 0..3839 = l*1280 + o*5 + d
    int l = bx / 1280;
    int r = bx - l * 1280;
    int o = r / 5;
    int d = r - o * 5;
    int i = threadIdx.x;
    const float* w = (l == 0) ? w1 : (l == 1) ? w2 : w3;
    wtb[(size_t)l * 327680 + (size_t)o * 1280 + d * 256 + i] =
        f2bf(w[(size_t)o * 1280 + i * 5 + d]);
}

// One block per (batch,token) row: sparse encode + packed bloom + bf16 copy
__global__ __launch_bounds__(256) void k_encode(const float* __restrict__ qx,
                                                const float* __restrict__ px,
                                                const float* __restrict__ wt,
                                                float* __restrict__ encoded,
                                                unsigned short* __restrict__ xbuf,
                                                unsigned* __restrict__ masks) {
    int row = blockIdx.x;              // 0..4607
    int b = row >> 4;
    const float* x = (b < NBQ) ? (qx + (size_t)row * CIN)
                               : (px + (size_t)(row - NBQ * LTOK) * CIN);
    __shared__ int idxs[2048];
    __shared__ int cnt;
    int tid = threadIdx.x;
    if (tid == 0) cnt = 0;
    __syncthreads();
    const float4* x4 = (const float4*)x;
#pragma unroll
    for (int j = 0; j < 8; ++j) {
        float4 v = x4[j * 256 + tid];
        int base = (j * 256 + tid) * 4;
        float vv[4] = {v.x, v.y, v.z, v.w};
#pragma unroll
        for (int c = 0; c < 4; ++c) {
            if (vv[c] != 0.f) {
                int k = base + c;
                int p = atomicAdd(&cnt, 1);
                if (p < 2048) idxs[p] = k;
                atomicOr(&masks[b * MASKW + (k >> 5)], 1u << (k & 31));
            }
        }
    }
    __syncthreads();
    int n = min(cnt, 2048);
    float acc = 0.f;
#pragma unroll 4
    for (int j = 0; j < n; ++j)
        acc += wt[(size_t)idxs[j] * H1 + tid];
    encoded[(size_t)row * H1 + tid] = acc;
    xbuf[(size_t)row * H1 + tid] = f2bf(acc);
}

__global__ __launch_bounds__(256) void k_qbits(const unsigned* __restrict__ masks,
                                               float* __restrict__ qbits) {
    __shared__ int red[256];
    int q = blockIdx.x, tid = threadIdx.x;
    red[tid] = __popc(masks[q * MASKW + tid]);
    __syncthreads();
    for (int st = 128; st > 0; st >>= 1) {
        if (tid < st) red[tid] += red[tid + st];
        __syncthreads();
    }
    if (tid == 0) qbits[q] = (float)red[0];
}

// MFMA conv block: 1 block/batch, 4 waves x 64 output channels.
// GEMM per layer: out[t in 16, o in 256] = sum_{d,i} WT[o][d][i] * xpad[t+d][i]
__global__ __launch_bounds__(256) void k_conv_mfma(
        const float* __restrict__ encoded,
        const unsigned short* __restrict__ xbuf,
        const unsigned short* __restrict__ wtb,
        const float* __restrict__ b1, const float* __restrict__ b2,
        const float* __restrict__ b3,
        float* __restrict__ emb) {
    int b = blockIdx.x;
    __shared__ unsigned short xls[2 * XBUFN];   // double-buffered padded activations
    __shared__ float xsum[256];
    int tid = threadIdx.x;
    int lane = tid & 63, wave = tid >> 6;
    int lane15 = lane & 15, quad = lane >> 4;
    int o0 = wave * 64;

    // zero both buffers (also zeroes the 2+2 pad rows, which stay zero)
    int* xi = (int*)xls;
    for (int i = tid; i < XBUFN; i += 256) xi[i] = 0;   // XBUFN ints == 2*XBUFN shorts
    __syncthreads();

    // stage layer-0 input rows t -> padded row t+2 of buffer 0 (int = 2 bf16)
    const int* xg = (const int*)(xbuf + (size_t)b * 16 * 256);
    for (int idx = tid; idx < 2048; idx += 256) {
        int t = idx >> 7, c = idx & 127;
        ((int*)xls)[((t + 2) * XROW >> 1) + c] = xg[idx];
    }
    // residual sum over tokens (fp32, coalesced)
    {
        float s = 0.f;
#pragma unroll
        for (int t = 0; t < 16; ++t) s += encoded[((size_t)b * 16 + t) * 256 + tid];
        xsum[tid] = s;
    }
    __syncthreads();

    const float* biases[3] = {b1, b2, b3};
    int cur = 0;
#pragma unroll 1
    for (int l = 0; l < 3; ++l) {
        const unsigned short* wl = wtb + (size_t)l * 327680 + (size_t)(o0 + lane15) * 1280;
        f32x4 acc[4];
#pragma unroll
        for (int f = 0; f < 4; ++f) acc[f] = (f32x4){0.f, 0.f, 0.f, 0.f};

        const unsigned short* xb = xls + cur * XBUFN;
#pragma unroll 1
        for (int d = 0; d < 5; ++d) {
            const unsigned short* arow = xb + (lane15 + d) * XROW + quad * 8;
            const unsigned short* brow = wl + d * 256 + quad * 8;
#pragma unroll 4
            for (int kk = 0; kk < 8; ++kk) {
                short8 a = *(const short8*)(arow + kk * 32);
#pragma unroll
                for (int f = 0; f < 4; ++f) {
                    short8 bf = *(const short8*)(brow + (size_t)f * 16 * 1280 + kk * 32);
                    acc[f] = __builtin_amdgcn_mfma_f32_16x16x32_bf16(a, bf, acc[f], 0, 0, 0);
                }
            }
        }

        float bias[4];
#pragma unroll
        for (int f = 0; f < 4; ++f) bias[f] = biases[l][o0 + f * 16 + lane15];

        if (l < 2) {
            unsigned short* nxt = xls + (1 - cur) * XBUFN;
            // C/D layout: col(o)=lane15, row(t)=quad*4+reg
#pragma unroll
            for (int f = 0; f < 4; ++f) {
                int o = o0 + f * 16 + lane15;
#pragma unroll
                for (int r = 0; r < 4; ++r) {
                    int t = quad * 4 + r;
                    float v = fmaxf(acc[f][r] + bias[f], 0.f);
                    nxt[(t + 2) * XROW + o] = f2bf(v);
                }
            }
            __syncthreads();
            cur = 1 - cur;
        } else {
            // fused relu + token-mean + residual
#pragma unroll
            for (int f = 0; f < 4; ++f) {
                float sf = 0.f;
#pragma unroll
                for (int r = 0; r < 4; ++r) sf += fmaxf(acc[f][r] + bias[f], 0.f);
                sf += __shfl_xor(sf, 16, 64);
                sf += __shfl_xor(sf, 32, 64);
                if (quad == 0) {
                    int o = o0 + f * 16 + lane15;
                    emb[b * 256 + o] = (sf + xsum[o]) * (1.f / 16.f);
                }
            }
        }
    }
}

// Cmat[b][o] = sum_i dec_w1[o][i + (b<32?0:256)] * relu(emb[b][i])
__global__ __launch_bounds__(256) void k_ab(const float* __restrict__ emb,
                                            const float* __restrict__ w1,
                                            float* __restrict__ Cmat) {
    int b = blockIdx.x, tid = threadIdx.x;
    __shared__ float e[256];
    __shared__ float red[256];
    e[tid] = fmaxf(emb[b * 256 + tid], 0.f);
    __syncthreads();
    int o = tid & 31, seg = tid >> 5;
    const float* wr = w1 + (size_t)o * 512 + (b < NBQ ? 0 : 256) + seg * 32;
    float s = 0.f;
#pragma unroll
    for (int i = 0; i < 32; ++i) s = fmaf(wr[i], e[seg * 32 + i], s);
    red[tid] = s; __syncthreads();
    if (tid < 128) red[tid] += red[tid + 128]; __syncthreads();
    if (tid < 64)  red[tid] += red[tid + 64];  __syncthreads();
    if (tid < 32) {
        red[tid] += red[tid + 32];
        Cmat[b * 32 + tid] = red[tid];
    }
}

// One block per (q,p) pair: tiny MLP + sparse masked decode
__global__ __launch_bounds__(256) void k_pair(const float* __restrict__ Cmat,
                                              const float* __restrict__ b1,
                                              const float* __restrict__ w2,
                                              const float* __restrict__ b2,
                                              const float* __restrict__ w3,
                                              const unsigned* __restrict__ masks,
                                              const float* __restrict__ qbits,
                                              float* __restrict__ desc) {
    int p = blockIdx.x, q = blockIdx.y;
    __shared__ float h1[32], h2[32];
    __shared__ float red[256];
    int tid = threadIdx.x;
    if (tid < 32)
        h1[tid] = fmaxf(Cmat[q * 32 + tid] + Cmat[(NBQ + p) * 32 + tid] + b1[tid], 0.f);
    __syncthreads();
    if (tid < 32) {
        float s = b2[tid];
#pragma unroll
        for (int j = 0; j < 32; ++j) s = fmaf(w2[tid * 32 + j], h1[j], s);
        h2[tid] = fmaxf(s, 0.f);
    }
    __syncthreads();
    float h2r[32];
#pragma unroll
    for (int j = 0; j < 32; ++j) h2r[j] = h2[j];
    unsigned m = masks[q * MASKW + tid] & masks[(NBQ + p) * MASKW + tid];
    float local = 0.f;
    while (m) {
        int bit = __ffs(m) - 1;
        m &= m - 1;
        int k = tid * 32 + bit;
        const float* r = w3 + (size_t)k * 32;
        float dot = 0.f;
#pragma unroll
        for (int j = 0; j < 32; ++j) dot = fmaf(h2r[j], r[j], dot);
        local += 1.f + (dot >= 0.f ? dot : dot * 0.125f);
    }
    float total = block_reduce_sum_256(local, red);
    if (tid == 0) desc[q * 256 + p] = total / qbits[q];
}

// One block per q row: normalize over p, fuse geo distance
__global__ __launch_bounds__(256) void k_final(const float* __restrict__ desc,
                                               const float* __restrict__ qloc,
                                               const float* __restrict__ ploc,
                                               const float* __restrict__ sa,
                                               const float* __restrict__ sb,
                                               const float* __restrict__ sc,
                                               const float* __restrict__ sd,
                                               float* __restrict__ out) {
    __shared__ float red[256];
    int q = blockIdx.x, tid = threadIdx.x;
    float v = desc[q * 256 + tid];
    float mean = block_reduce_sum_256(v, red) * (1.f / 256.f);
    float dv = v - mean;
    float var = block_reduce_sum_256(dv * dv, red) * (1.f / 255.f);
    float norm = dv / (sqrtf(var) + 1e-6f);
    float dx = qloc[q * 2]     - ploc[tid * 2];
    float dy = qloc[q * 2 + 1] - ploc[tid * 2 + 1];
    float dist = sqrtf(dx * dx + dy * dy);
    float z = sa[0] * norm + sb[0];
    float sig = 1.f / (1.f + expf(-z));
    out[q * 256 + tid] = (sc[0] - sig) * (-logf(dist + 1.f) - sd[0]);
}

extern "C" void kernel_launch(void* const* d_in, const int* in_sizes, int n_in,
                              void* d_out, int out_size, void* d_ws, size_t ws_size,
                              hipStream_t stream) {
    const float* qx   = (const float*)d_in[0];
    const float* qloc = (const float*)d_in[1];
    const float* px   = (const float*)d_in[2];
    const float* ploc = (const float*)d_in[3];
    const float* encw = (const float*)d_in[4];
    const float* cw1  = (const float*)d_in[5];
    const float* cb1  = (const float*)d_in[6];
    const float* cw2  = (const float*)d_in[7];
    const float* cb2  = (const float*)d_in[8];
    const float* cw3  = (const float*)d_in[9];
    const float* cb3  = (const float*)d_in[10];
    const float* dw1  = (const float*)d_in[11];
    const float* db1  = (const float*)d_in[12];
    const float* dw2  = (const float*)d_in[13];
    const float* db2  = (const float*)d_in[14];
    const float* dw3  = (const float*)d_in[15];
    const float* sa   = (const float*)d_in[16];
    const float* sb   = (const float*)d_in[17];
    const float* sc   = (const float*)d_in[18];
    const float* sd   = (const float*)d_in[19];

    char* w = (char*)d_ws;
    float*          enc_wT  = (float*)w;          w += (size_t)CIN * H1 * 4;        // 8 MB
    float*          encoded = (float*)w;          w += (size_t)NB * LTOK * H1 * 4;  // 4.5 MB
    unsigned short* xbuf    = (unsigned short*)w; w += (size_t)NB * LTOK * H1 * 2;  // 2.25 MB
    unsigned short* wtb     = (unsigned short*)w; w += (size_t)3 * 256 * 1280 * 2;  // 1.97 MB
    float*          emb     = (float*)w;          w += (size_t)NB * H1 * 4;
    float*          Cmat    = (float*)w;          w += (size_t)NB * H2 * 4;
    unsigned*       masks   = (unsigned*)w;       w += (size_t)NB * MASKW * 4;
    float*          qbits   = (float*)w;          w += 1024;
    float*          desc    = (float*)w;          w += (size_t)NBQ * NBP * 4;

    hipMemsetAsync(masks, 0, (size_t)NB * MASKW * 4, stream);
    k_transpose<<<dim3(CIN / 32, H1 / 32), 256, 0, stream>>>(encw, enc_wT);
    k_wprep<<<3840, 256, 0, stream>>>(cw1, cw2, cw3, wtb);
    k_encode<<<NB * LTOK, 256, 0, stream>>>(qx, px, enc_wT, encoded, xbuf, masks);
    k_qbits<<<NBQ, 256, 0, stream>>>(masks, qbits);
    k_conv_mfma<<<NB, 256, 0, stream>>>(encoded, xbuf, wtb, cb1, cb2, cb3, emb);
    k_ab<<<NB, 256, 0, stream>>>(emb, dw1, Cmat);
    k_pair<<<dim3(NBP, NBQ), 256, 0, stream>>>(Cmat, db1, dw2, db2, dw3, masks, qbits, desc);
    k_final<<<NBQ, 256, 0, stream>>>(desc, qloc, ploc, sa, sb, sc, sd, (float*)d_out);
}

// Round 3
// 364.615 us; speedup vs baseline: 1.6097x; 1.2049x over previous
//
#include <hip/hip_runtime.h>

#define NB 288          // 32 query + 256 poi batches
#define NBQ 32
#define NBP 256
#define LTOK 16
#define CIN 8192
#define H1 256
#define H2 32
#define MASKW 256       // 8192 bits / 32
#define XROW 264        // padded LDS row stride (bf16 elems) -> spread banks

typedef __attribute__((ext_vector_type(8))) short short8;   // 8 bf16 = 4 VGPRs
typedef __attribute__((ext_vector_type(4))) float f32x4;

__device__ __forceinline__ unsigned short f2bf(float f) {
    unsigned u = __float_as_uint(f);
    u += 0x7fffu + ((u >> 16) & 1u);
    return (unsigned short)(u >> 16);
}

__device__ __forceinline__ float block_reduce_sum_256(float v, float* red) {
    int tid = threadIdx.x;
    red[tid] = v; __syncthreads();
    for (int st = 128; st > 0; st >>= 1) {
        if (tid < st) red[tid] += red[tid + st];
        __syncthreads();
    }
    float r = red[0];
    __syncthreads();
    return r;
}

// enc_w (256, 8192) -> enc_wT (8192, 256) fp32
__global__ __launch_bounds__(256) void k_transpose(const float* __restrict__ w,
                                                   float* __restrict__ wt) {
    __shared__ float tile[32][33];
    int k0 = blockIdx.x * 32;
    int h0 = blockIdx.y * 32;
    int tx = threadIdx.x & 31, ty = threadIdx.x >> 5;
#pragma unroll
    for (int i = 0; i < 32; i += 8)
        tile[ty + i][tx] = w[(h0 + ty + i) * CIN + k0 + tx];
    __syncthreads();
#pragma unroll
    for (int i = 0; i < 32; i += 8)
        wt[(size_t)(k0 + ty + i) * H1 + h0 + tx] = tile[tx][ty + i];
}

// conv weights w[o][i][d] fp32 -> WT bf16 [l][o][d][i]
__global__ __launch_bounds__(256) void k_wprep(const float* __restrict__ w1,
                                               const float* __restrict__ w2,
                                               const float* __restrict__ w3,
                                               unsigned short* __restrict__ wtb) {
    int bx = blockIdx.x;                 // 0..3839 = l*1280 + o*5 + d
    int l = bx / 1280;
    int r = bx - l * 1280;
    int o = r / 5;
    int d = r - o * 5;
    int i = threadIdx.x;
    const float* w = (l == 0) ? w1 : (l == 1) ? w2 : w3;
    wtb[(size_t)l * 327680 + (size_t)o * 1280 + d * 256 + i] =
        f2bf(w[(size_t)o * 1280 + i * 5 + d]);
}

// One block per (batch,token) row: sparse encode + packed bloom + bf16 copy
__global__ __launch_bounds__(256) void k_encode(const float* __restrict__ qx,
                                                const float* __restrict__ px,
                                                const float* __restrict__ wt,
                                                float* __restrict__ encoded,
                                                unsigned short* __restrict__ xbuf,
                                                unsigned* __restrict__ masks) {
    int row = blockIdx.x;              // 0..4607
    int b = row >> 4;
    const float* x = (b < NBQ) ? (qx + (size_t)row * CIN)
                               : (px + (size_t)(row - NBQ * LTOK) * CIN);
    __shared__ int idxs[2048];
    __shared__ int cnt;
    int tid = threadIdx.x;
    if (tid == 0) cnt = 0;
    __syncthreads();
    const float4* x4 = (const float4*)x;
#pragma unroll
    for (int j = 0; j < 8; ++j) {
        float4 v = x4[j * 256 + tid];
        int base = (j * 256 + tid) * 4;
        float vv[4] = {v.x, v.y, v.z, v.w};
#pragma unroll
        for (int c = 0; c < 4; ++c) {
            if (vv[c] != 0.f) {
                int k = base + c;
                int p = atomicAdd(&cnt, 1);
                if (p < 2048) idxs[p] = k;
                atomicOr(&masks[b * MASKW + (k >> 5)], 1u << (k & 31));
            }
        }
    }
    __syncthreads();
    int n = min(cnt, 2048);
    float acc = 0.f;
#pragma unroll 4
    for (int j = 0; j < n; ++j)
        acc += wt[(size_t)idxs[j] * H1 + tid];
    encoded[(size_t)row * H1 + tid] = acc;
    xbuf[(size_t)row * H1 + tid] = f2bf(acc);
}

__global__ __launch_bounds__(256) void k_qbits(const unsigned* __restrict__ masks,
                                               float* __restrict__ qbits) {
    __shared__ int red[256];
    int q = blockIdx.x, tid = threadIdx.x;
    red[tid] = __popc(masks[q * MASKW + tid]);
    __syncthreads();
    for (int st = 128; st > 0; st >>= 1) {
        if (tid < st) red[tid] += red[tid + st];
        __syncthreads();
    }
    if (tid == 0) qbits[q] = (float)red[0];
}

// Batched conv layer GEMM: out[r=(b,t) in 4608][o in 256] =
//   relu(bias[o] + sum_d sum_i W[o][d][i] * in[b*16+t+d-2][i])  (zero-padded t)
// Block tile 64x64 (4 batches x 64 outs), grid (72, 4), 4 waves of 32x32.
// A staged once in LDS (padded rows); B staged per-tap with reg prefetch.
__global__ __launch_bounds__(256) void k_cgemm(const unsigned short* __restrict__ actIn,
                                               unsigned short* __restrict__ actOut,
                                               float* __restrict__ actOutF,
                                               const unsigned short* __restrict__ wl,
                                               const float* __restrict__ bias,
                                               int last) {
    __shared__ unsigned short Als[4 * 20 * XROW];   // 42.2 KB
    __shared__ unsigned short Bls[64 * XROW];       // 33.8 KB
    int tid = threadIdx.x;
    int m0 = blockIdx.x * 64, n0 = blockIdx.y * 64;

    // zero A (covers the 2+2 pad rows per batch)
    int* Ai = (int*)Als;
#pragma unroll
    for (int i = tid; i < 4 * 20 * XROW / 2; i += 256) Ai[i] = 0;
    __syncthreads();

    // fill A rows (64 rows x 512B, 4 threads/row) + prefetch B tap 0 into regs
    int row = tid >> 2, part = tid & 3;
    {
        const short8* src = (const short8*)(actIn + (size_t)(m0 + row) * 256 + part * 64);
        unsigned short* dst = Als + ((row >> 4) * 20 + (row & 15) + 2) * XROW + part * 64;
#pragma unroll
        for (int j = 0; j < 8; ++j) *(short8*)(dst + j * 8) = src[j];
    }
    const unsigned short* bsrc = wl + (size_t)(n0 + row) * 1280 + part * 64;
    short8 rb[8];
#pragma unroll
    for (int j = 0; j < 8; ++j) rb[j] = *(const short8*)(bsrc + j * 8);

    int lane = tid & 63, wave = tid >> 6;
    int lane15 = lane & 15, quad = lane >> 4;
    int wm = wave & 1, wn = wave >> 1;
    const unsigned short* Aw = Als + (wm * 2) * 20 * XROW;      // wave's 2 batches
    const unsigned short* Bw = Bls + (wn * 32) * XROW;          // wave's 32 outputs
    unsigned short* bdst = Bls + row * XROW + part * 64;

    f32x4 acc[2][2];
#pragma unroll
    for (int mi = 0; mi < 2; ++mi)
#pragma unroll
        for (int ni = 0; ni < 2; ++ni) acc[mi][ni] = (f32x4){0.f, 0.f, 0.f, 0.f};

#pragma unroll 1
    for (int d = 0; d < 5; ++d) {
#pragma unroll
        for (int j = 0; j < 8; ++j) *(short8*)(bdst + j * 8) = rb[j];
        __syncthreads();
        if (d < 4) {
            const unsigned short* s2 = bsrc + (d + 1) * 256;
#pragma unroll
            for (int j = 0; j < 8; ++j) rb[j] = *(const short8*)(s2 + j * 8);
        }
        const unsigned short* a0 = Aw + (lane15 + d) * XROW + quad * 8;
        const unsigned short* a1 = a0 + 20 * XROW;
        const unsigned short* b0 = Bw + lane15 * XROW + quad * 8;
        const unsigned short* b1 = b0 + 16 * XROW;
#pragma unroll
        for (int kk = 0; kk < 8; ++kk) {
            short8 av0 = *(const short8*)(a0 + kk * 32);
            short8 av1 = *(const short8*)(a1 + kk * 32);
            short8 bv0 = *(const short8*)(b0 + kk * 32);
            short8 bv1 = *(const short8*)(b1 + kk * 32);
            acc[0][0] = __builtin_amdgcn_mfma_f32_16x16x32_bf16(av0, bv0, acc[0][0], 0, 0, 0);
            acc[0][1] = __builtin_amdgcn_mfma_f32_16x16x32_bf16(av0, bv1, acc[0][1], 0, 0, 0);
            acc[1][0] = __builtin_amdgcn_mfma_f32_16x16x32_bf16(av1, bv0, acc[1][0], 0, 0, 0);
            acc[1][1] = __builtin_amdgcn_mfma_f32_16x16x32_bf16(av1, bv1, acc[1][1], 0, 0, 0);
        }
        __syncthreads();
    }

    // epilogue: relu(+bias); C layout col(o)=lane15, row(t)=quad*4+reg
#pragma unroll
    for (int ni = 0; ni < 2; ++ni) {
        int o = n0 + wn * 32 + ni * 16 + lane15;
        float bv = bias[o];
#pragma unroll
        for (int mi = 0; mi < 2; ++mi) {
            int rbase = m0 + wm * 32 + mi * 16 + quad * 4;
#pragma unroll
            for (int r = 0; r < 4; ++r) {
                float v = fmaxf(acc[mi][ni][r] + bv, 0.f);
                if (last) actOutF[(size_t)(rbase + r) * 256 + o] = v;
                else      actOut[(size_t)(rbase + r) * 256 + o] = f2bf(v);
            }
        }
    }
}

// e = relu((sum_t conv3_out + sum_t encoded)/16); Cmat[b][o] = dec_w1 half . e
__global__ __launch_bounds__(256) void k_ab(const float* __restrict__ actF,
                                            const float* __restrict__ encoded,
                                            const float* __restrict__ w1,
                                            float* __restrict__ Cmat) {
    int b = blockIdx.x, tid = threadIdx.x;
    __shared__ float e[256];
    __shared__ float red[256];
    float s = 0.f;
#pragma unroll
    for (int t = 0; t < 16; ++t)
        s += actF[((size_t)b * 16 + t) * 256 + tid] + encoded[((size_t)b * 16 + t) * 256 + tid];
    e[tid] = fmaxf(s * (1.f / 16.f), 0.f);
    __syncthreads();
    int o = tid & 31, seg = tid >> 5;
    const float* wr = w1 + (size_t)o * 512 + (b < NBQ ? 0 : 256) + seg * 32;
    float v = 0.f;
#pragma unroll
    for (int i = 0; i < 32; ++i) v = fmaf(wr[i], e[seg * 32 + i], v);
    red[tid] = v; __syncthreads();
    if (tid < 128) red[tid] += red[tid + 128]; __syncthreads();
    if (tid < 64)  red[tid] += red[tid + 64];  __syncthreads();
    if (tid < 32) {
        red[tid] += red[tid + 32];
        Cmat[b * 32 + tid] = red[tid];
    }
}

// One block per (q,p): tiny MLP + compacted sparse decode, 8 lanes per W3 row
__global__ __launch_bounds__(256) void k_pair(const float* __restrict__ Cmat,
                                              const float* __restrict__ b1,
                                              const float* __restrict__ w2,
                                              const float* __restrict__ b2,
                                              const float* __restrict__ w3,
                                              const unsigned* __restrict__ masks,
                                              const float* __restrict__ qbits,
                                              float* __restrict__ desc) {
    int p = blockIdx.x, q = blockIdx.y;
    __shared__ float h1[32];
    __shared__ __align__(16) float h2s[32];
    __shared__ int idxs[3072];
    __shared__ int cnt;
    __shared__ float red[256];
    int tid = threadIdx.x;
    if (tid == 0) cnt = 0;
    __syncthreads();
    // compact AND-mask set bits into a balanced index list
    unsigned m = masks[q * MASKW + tid] & masks[(NBQ + p) * MASKW + tid];
    int nb = __popc(m);
    if (nb) {
        int pos = atomicAdd(&cnt, nb);
        while (m) {
            int bit = __ffs(m) - 1;
            m &= m - 1;
            idxs[pos++] = tid * 32 + bit;
        }
    }
    if (tid < 32)
        h1[tid] = fmaxf(Cmat[q * 32 + tid] + Cmat[(NBQ + p) * 32 + tid] + b1[tid], 0.f);
    __syncthreads();
    if (tid < 32) {
        float s = b2[tid];
#pragma unroll
        for (int j = 0; j < 32; ++j) s = fmaf(w2[tid * 32 + j], h1[j], s);
        h2s[tid] = fmaxf(s, 0.f);
    }
    __syncthreads();
    int n = cnt;
    int rowi = tid >> 3, part = tid & 7;          // 32 rows/iter, 8 lanes/row
    float4 h = ((const float4*)h2s)[part];
    float local = 0.f;
    for (int base = 0; base < n; base += 32) {
        int r = base + rowi;
        bool act = r < n;
        float dot = 0.f;
        if (act) {
            float4 wv = *(const float4*)(w3 + (size_t)idxs[r] * 32 + part * 4);
            dot = wv.x * h.x + wv.y * h.y + wv.z * h.z + wv.w * h.w;
        }
        dot += __shfl_xor(dot, 1);
        dot += __shfl_xor(dot, 2);
        dot += __shfl_xor(dot, 4);
        if (act && part == 0)
            local += 1.f + (dot >= 0.f ? dot : dot * 0.125f);
    }
    float total = block_reduce_sum_256(local, red);
    if (tid == 0) desc[q * 256 + p] = total / qbits[q];
}

// One block per q row: normalize over p, fuse geo distance
__global__ __launch_bounds__(256) void k_final(const float* __restrict__ desc,
                                               const float* __restrict__ qloc,
                                               const float* __restrict__ ploc,
                                               const float* __restrict__ sa,
                                               const float* __restrict__ sb,
                                               const float* __restrict__ sc,
                                               const float* __restrict__ sd,
                                               float* __restrict__ out) {
    __shared__ float red[256];
    int q = blockIdx.x, tid = threadIdx.x;
    float v = desc[q * 256 + tid];
    float mean = block_reduce_sum_256(v, red) * (1.f / 256.f);
    float dv = v - mean;
    float var = block_reduce_sum_256(dv * dv, red) * (1.f / 255.f);
    float norm = dv / (sqrtf(var) + 1e-6f);
    float dx = qloc[q * 2]     - ploc[tid * 2];
    float dy = qloc[q * 2 + 1] - ploc[tid * 2 + 1];
    float dist = sqrtf(dx * dx + dy * dy);
    float z = sa[0] * norm + sb[0];
    float sig = 1.f / (1.f + expf(-z));
    out[q * 256 + tid] = (sc[0] - sig) * (-logf(dist + 1.f) - sd[0]);
}

extern "C" void kernel_launch(void* const* d_in, const int* in_sizes, int n_in,
                              void* d_out, int out_size, void* d_ws, size_t ws_size,
                              hipStream_t stream) {
    const float* qx   = (const float*)d_in[0];
    const float* qloc = (const float*)d_in[1];
    const float* px   = (const float*)d_in[2];
    const float* ploc = (const float*)d_in[3];
    const float* encw = (const float*)d_in[4];
    const float* cw1  = (const float*)d_in[5];
    const float* cb1  = (const float*)d_in[6];
    const float* cw2  = (const float*)d_in[7];
    const float* cb2  = (const float*)d_in[8];
    const float* cw3  = (const float*)d_in[9];
    const float* cb3  = (const float*)d_in[10];
    const float* dw1  = (const float*)d_in[11];
    const float* db1  = (const float*)d_in[12];
    const float* dw2  = (const float*)d_in[13];
    const float* db2  = (const float*)d_in[14];
    const float* dw3  = (const float*)d_in[15];
    const float* sa   = (const float*)d_in[16];
    const float* sb   = (const float*)d_in[17];
    const float* sc   = (const float*)d_in[18];
    const float* sd   = (const float*)d_in[19];

    char* w = (char*)d_ws;
    float*          enc_wT  = (float*)w;          w += (size_t)CIN * H1 * 4;        // 8 MB
    float*          encoded = (float*)w;          w += (size_t)NB * LTOK * H1 * 4;  // 4.5 MB
    unsigned short* xbuf    = (unsigned short*)w; w += (size_t)NB * LTOK * H1 * 2;  // 2.25 MB
    unsigned short* act1    = (unsigned short*)w; w += (size_t)NB * LTOK * H1 * 2;  // 2.25 MB
    unsigned short* act2    = (unsigned short*)w; w += (size_t)NB * LTOK * H1 * 2;  // 2.25 MB
    float*          actF    = (float*)w;          w += (size_t)NB * LTOK * H1 * 4;  // 4.5 MB
    unsigned short* wtb     = (unsigned short*)w; w += (size_t)3 * 256 * 1280 * 2;  // 1.97 MB
    float*          Cmat    = (float*)w;          w += (size_t)NB * H2 * 4;
    unsigned*       masks   = (unsigned*)w;       w += (size_t)NB * MASKW * 4;
    float*          qbits   = (float*)w;          w += 1024;
    float*          desc    = (float*)w;          w += (size_t)NBQ * NBP * 4;

    hipMemsetAsync(masks, 0, (size_t)NB * MASKW * 4, stream);
    k_transpose<<<dim3(CIN / 32, H1 / 32), 256, 0, stream>>>(encw, enc_wT);
    k_wprep<<<3840, 256, 0, stream>>>(cw1, cw2, cw3, wtb);
    k_encode<<<NB * LTOK, 256, 0, stream>>>(qx, px, enc_wT, encoded, xbuf, masks);
    k_qbits<<<NBQ, 256, 0, stream>>>(masks, qbits);
    dim3 cgrid(NB * LTOK / 64, 4);
    k_cgemm<<<cgrid, 256, 0, stream>>>(xbuf, act1, actF, wtb,              cb1, 0);
    k_cgemm<<<cgrid, 256, 0, stream>>>(act1, act2, actF, wtb + 327680,     cb2, 0);
    k_cgemm<<<cgrid, 256, 0, stream>>>(act2, act1, actF, wtb + 2 * 327680, cb3, 1);
    k_ab<<<NB, 256, 0, stream>>>(actF, encoded, dw1, Cmat);
    k_pair<<<dim3(NBP, NBQ), 256, 0, stream>>>(Cmat, db1, dw2, db2, dw3, masks, qbits, desc);
    k_final<<<NBQ, 256, 0, stream>>>(desc, qloc, ploc, sa, sb, sc, sd, (float*)d_out);
}

// Round 4
// 359.198 us; speedup vs baseline: 1.6340x; 1.0151x over previous
//
#include <hip/hip_runtime.h>

#define NB 288          // 32 query + 256 poi batches
#define NBQ 32
#define NBP 256
#define LTOK 16
#define CIN 8192
#define H1 256
#define H2 32
#define MASKW 256       // 8192 bits / 32
#define XROW 264        // padded LDS row stride (bf16 elems)
#define IDXCAP 208      // idx-list slots per row (mean 82, +12 sigma safe, 16B aligned)

typedef __attribute__((ext_vector_type(8))) short short8;   // 8 bf16 = 4 VGPRs
typedef __attribute__((ext_vector_type(4))) float f32x4;

__device__ __forceinline__ unsigned short f2bf(float f) {
    unsigned u = __float_as_uint(f);
    u += 0x7fffu + ((u >> 16) & 1u);
    return (unsigned short)(u >> 16);
}

// enc_w (256,8192) fp32 -> wtp[k][pair] packed 2xbf16 (ch 2p low, 2p+1 high)
__global__ __launch_bounds__(256) void k_transpose_pack(const float* __restrict__ w,
                                                        unsigned* __restrict__ wtp) {
    __shared__ float tile[32][33];
    int k0 = blockIdx.x * 32;          // along 8192
    int h0 = blockIdx.y * 32;          // along 256
    int tx = threadIdx.x & 31, ty = threadIdx.x >> 5;
#pragma unroll
    for (int i = 0; i < 32; i += 8)
        tile[ty + i][tx] = w[(h0 + ty + i) * CIN + k0 + tx];   // tile[h_local][k_local]
    __syncthreads();
    int kl = threadIdx.x >> 3, pw = threadIdx.x & 7;
#pragma unroll
    for (int u = 0; u < 2; ++u) {
        int p = pw + u * 8;            // pair within h-tile, 0..15
        unsigned lo = f2bf(tile[2 * p][kl]);
        unsigned hi = f2bf(tile[2 * p + 1][kl]);
        wtp[(size_t)(k0 + kl) * 128 + (h0 >> 1) + p] = (hi << 16) | lo;
    }
}

// conv weights w[o][i][d] fp32 -> WT bf16 [l][o][d][i]; also zero wtp sentinel row
__global__ __launch_bounds__(256) void k_wprep(const float* __restrict__ w1,
                                               const float* __restrict__ w2,
                                               const float* __restrict__ w3,
                                               unsigned short* __restrict__ wtb,
                                               unsigned* __restrict__ wtp) {
    int bx = blockIdx.x;                 // 0..3839 = l*1280 + o*5 + d
    if (bx == 0 && threadIdx.x < 128) wtp[(size_t)8192 * 128 + threadIdx.x] = 0;  // sentinel
    int l = bx / 1280;
    int r = bx - l * 1280;
    int o = r / 5;
    int d = r - o * 5;
    int i = threadIdx.x;
    const float* w = (l == 0) ? w1 : (l == 1) ? w2 : w3;
    wtb[(size_t)l * 327680 + (size_t)o * 1280 + d * 256 + i] =
        f2bf(w[(size_t)o * 1280 + i * 5 + d]);
}

// Pure HBM scan: one block per (batch,token) row -> idx list + batch masks
__global__ __launch_bounds__(256) void k_scan(const float* __restrict__ qx,
                                              const float* __restrict__ px,
                                              int* __restrict__ idxl,
                                              int* __restrict__ cnts,
                                              unsigned* __restrict__ masks) {
    int row = blockIdx.x;              // 0..4607
    int b = row >> 4;
    const float* x = (b < NBQ) ? (qx + (size_t)row * CIN)
                               : (px + (size_t)(row - NBQ * LTOK) * CIN);
    __shared__ int cnt;
    int tid = threadIdx.x;
    if (tid == 0) cnt = 0;
    __syncthreads();
    int* il = idxl + (size_t)row * IDXCAP;
    const float4* x4 = (const float4*)x;
#pragma unroll
    for (int j = 0; j < 8; ++j) {
        float4 v = x4[j * 256 + tid];
        unsigned ox = __float_as_uint(v.x) | __float_as_uint(v.y) |
                      __float_as_uint(v.z) | __float_as_uint(v.w);
        if (ox) {
            int base = (j * 256 + tid) * 4;
            float vv[4] = {v.x, v.y, v.z, v.w};
#pragma unroll
            for (int c = 0; c < 4; ++c) {
                if (vv[c] != 0.f) {
                    int k = base + c;
                    int p = atomicAdd(&cnt, 1);
                    if (p < 192) il[p] = k;
                    atomicOr(&masks[b * MASKW + (k >> 5)], 1u << (k & 31));
                }
            }
        }
    }
    __syncthreads();
    int n = min(cnt, 192);
    if (tid == 0) cnts[row] = n;
    for (int i = n + tid; i < 200; i += 256) il[i] = 8192;   // sentinel pad
}

// Gather: 1 row/block, 128 threads = channel pairs; bf16 packed table, unroll 8
__global__ __launch_bounds__(128) void k_gather(const unsigned* __restrict__ wtp,
                                                const int* __restrict__ idxl,
                                                const int* __restrict__ cnts,
                                                float* __restrict__ encoded,
                                                unsigned* __restrict__ xbufu) {
    int row = blockIdx.x, tid = threadIdx.x;
    int n = cnts[row];
    const int* il = idxl + (size_t)row * IDXCAP;
    float aL = 0.f, aH = 0.f;
    for (int j = 0; j < n; j += 8) {
        int4 ia = *(const int4*)(il + j);
        int4 ib = *(const int4*)(il + j + 4);
        int id[8] = {ia.x, ia.y, ia.z, ia.w, ib.x, ib.y, ib.z, ib.w};
#pragma unroll
        for (int u = 0; u < 8; ++u) {
            unsigned v = wtp[(size_t)id[u] * 128 + tid];
            aL += __uint_as_float(v << 16);
            aH += __uint_as_float(v & 0xffff0000u);
        }
    }
    ((float2*)encoded)[(size_t)row * 128 + tid] = float2{aL, aH};
    unsigned bl = f2bf(aL), bh = f2bf(aH);
    xbufu[(size_t)row * 128 + tid] = (bh << 16) | bl;
}

__global__ __launch_bounds__(256) void k_qbits(const unsigned* __restrict__ masks,
                                               float* __restrict__ qbits) {
    __shared__ int red[256];
    int q = blockIdx.x, tid = threadIdx.x;
    red[tid] = __popc(masks[q * MASKW + tid]);
    __syncthreads();
    for (int st = 128; st > 0; st >>= 1) {
        if (tid < st) red[tid] += red[tid + st];
        __syncthreads();
    }
    if (tid == 0) qbits[q] = (float)red[0];
}

// Conv layer GEMM, 32 rows (2 batches) x 32 outs per block, grid (144,8).
// LDS 38 KB -> 4 blocks/CU. 4 waves: quadrant (wm rows16, wn outs16).
__global__ __launch_bounds__(256) void k_cgemm(const unsigned short* __restrict__ actIn,
                                               unsigned short* __restrict__ actOut,
                                               float* __restrict__ actOutF,
                                               const unsigned short* __restrict__ wl,
                                               const float* __restrict__ bias,
                                               int last) {
    __shared__ unsigned short Als[2 * 20 * XROW];   // 21.1 KB
    __shared__ unsigned short Bls[32 * XROW];       // 16.9 KB
    int tid = threadIdx.x;
    int m0 = blockIdx.x * 32, n0 = blockIdx.y * 32;

    int* Ai = (int*)Als;
#pragma unroll
    for (int i = tid; i < 20 * XROW; i += 256) Ai[i] = 0;   // 20*XROW ints = whole Als
    __syncthreads();

    int row = tid >> 3, part = tid & 7;       // 32 rows, 64B per thread
    {
        const short8* src = (const short8*)(actIn + (size_t)(m0 + row) * 256 + part * 32);
        unsigned short* dst = Als + ((row >> 4) * 20 + (row & 15) + 2) * XROW + part * 32;
#pragma unroll
        for (int j = 0; j < 4; ++j) *(short8*)(dst + j * 8) = src[j];
    }
    const unsigned short* bsrc = wl + (size_t)(n0 + row) * 1280 + part * 32;
    short8 rb[4];
#pragma unroll
    for (int j = 0; j < 4; ++j) rb[j] = *(const short8*)(bsrc + j * 8);

    int lane = tid & 63, wave = tid >> 6;
    int lane15 = lane & 15, quad = lane >> 4;
    int wm = wave & 1, wn = wave >> 1;
    unsigned short* bdst = Bls + row * XROW + part * 32;

    f32x4 acc = (f32x4){0.f, 0.f, 0.f, 0.f};

#pragma unroll 1
    for (int d = 0; d < 5; ++d) {
#pragma unroll
        for (int j = 0; j < 4; ++j) *(short8*)(bdst + j * 8) = rb[j];
        __syncthreads();
        if (d < 4) {
            const unsigned short* s2 = bsrc + (d + 1) * 256;
#pragma unroll
            for (int j = 0; j < 4; ++j) rb[j] = *(const short8*)(s2 + j * 8);
        }
        const unsigned short* ap = Als + (wm * 20 + lane15 + d) * XROW + quad * 8;
        const unsigned short* bp = Bls + (wn * 16 + lane15) * XROW + quad * 8;
#pragma unroll
        for (int kk = 0; kk < 8; ++kk) {
            short8 av = *(const short8*)(ap + kk * 32);
            short8 bv = *(const short8*)(bp + kk * 32);
            acc = __builtin_amdgcn_mfma_f32_16x16x32_bf16(av, bv, acc, 0, 0, 0);
        }
        __syncthreads();
    }

    int o = n0 + wn * 16 + lane15;
    float bv = bias[o];
    int rbase = m0 + wm * 16 + quad * 4;
#pragma unroll
    for (int r = 0; r < 4; ++r) {
        float v = fmaxf(acc[r] + bv, 0.f);
        if (last) actOutF[(size_t)(rbase + r) * 256 + o] = v;
        else      actOut[(size_t)(rbase + r) * 256 + o] = f2bf(v);
    }
}

// e = relu((sum_t conv3 + sum_t encoded)/16); Cmat[b][o] = dec_w1 half . e
__global__ __launch_bounds__(256) void k_ab(const float* __restrict__ actF,
                                            const float* __restrict__ encoded,
                                            const float* __restrict__ w1,
                                            float* __restrict__ Cmat) {
    int b = blockIdx.x, tid = threadIdx.x;
    __shared__ float e[256];
    __shared__ float red[256];
    float s = 0.f;
#pragma unroll
    for (int t = 0; t < 16; ++t)
        s += actF[((size_t)b * 16 + t) * 256 + tid] + encoded[((size_t)b * 16 + t) * 256 + tid];
    e[tid] = fmaxf(s * (1.f / 16.f), 0.f);
    __syncthreads();
    int o = tid & 31, seg = tid >> 5;
    const float* wr = w1 + (size_t)o * 512 + (b < NBQ ? 0 : 256) + seg * 32;
    float v = 0.f;
#pragma unroll
    for (int i = 0; i < 32; ++i) v = fmaf(wr[i], e[seg * 32 + i], v);
    red[tid] = v; __syncthreads();
    if (tid < 128) red[tid] += red[tid + 128]; __syncthreads();
    if (tid < 64)  red[tid] += red[tid + 64];  __syncthreads();
    if (tid < 32) {
        red[tid] += red[tid + 32];
        Cmat[b * 32 + tid] = red[tid];
    }
}

// One block per (q,p): tiny MLP + compacted sparse decode, 8 lanes per W3 row
__global__ __launch_bounds__(256) void k_pair(const float* __restrict__ Cmat,
                                              const float* __restrict__ b1,
                                              const float* __restrict__ w2,
                                              const float* __restrict__ b2,
                                              const float* __restrict__ w3,
                                              const unsigned* __restrict__ masks,
                                              const float* __restrict__ qbits,
                                              float* __restrict__ desc) {
    int p = blockIdx.x, q = blockIdx.y;
    __shared__ float h1[32];
    __shared__ __align__(16) float h2s[32];
    __shared__ int idxs[3072];
    __shared__ int cnt;
    __shared__ float wsum[4];
    int tid = threadIdx.x;
    if (tid == 0) cnt = 0;
    __syncthreads();
    unsigned m = masks[q * MASKW + tid] & masks[(NBQ + p) * MASKW + tid];
    int nb = __popc(m);
    if (nb) {
        int pos = atomicAdd(&cnt, nb);
        while (m) {
            int bit = __ffs(m) - 1;
            m &= m - 1;
            idxs[pos++] = tid * 32 + bit;
        }
    }
    if (tid < 32)
        h1[tid] = fmaxf(Cmat[q * 32 + tid] + Cmat[(NBQ + p) * 32 + tid] + b1[tid], 0.f);
    __syncthreads();
    if (tid < 32) {
        float s = b2[tid];
#pragma unroll
        for (int j = 0; j < 32; ++j) s = fmaf(w2[tid * 32 + j], h1[j], s);
        h2s[tid] = fmaxf(s, 0.f);
    }
    __syncthreads();
    int n = cnt;
    int rowi = tid >> 3, part = tid & 7;          // 32 rows/iter, 8 lanes/row
    float4 h = ((const float4*)h2s)[part];
    float local = 0.f;
    for (int base = 0; base < n; base += 32) {
        int r = base + rowi;
        bool act = r < n;
        float dot = 0.f;
        if (act) {
            float4 wv = *(const float4*)(w3 + (size_t)idxs[r] * 32 + part * 4);
            dot = wv.x * h.x + wv.y * h.y + wv.z * h.z + wv.w * h.w;
        }
        dot += __shfl_xor(dot, 1);
        dot += __shfl_xor(dot, 2);
        dot += __shfl_xor(dot, 4);
        if (act && part == 0)
            local += 1.f + (dot >= 0.f ? dot : dot * 0.125f);
    }
#pragma unroll
    for (int st = 1; st < 64; st <<= 1) local += __shfl_xor(local, st);
    if ((tid & 63) == 0) wsum[tid >> 6] = local;
    __syncthreads();
    if (tid == 0)
        desc[q * 256 + p] = (wsum[0] + wsum[1] + wsum[2] + wsum[3]) / qbits[q];
}

// One block per q row: normalize over p, fuse geo distance
__global__ __launch_bounds__(256) void k_final(const float* __restrict__ desc,
                                               const float* __restrict__ qloc,
                                               const float* __restrict__ ploc,
                                               const float* __restrict__ sa,
                                               const float* __restrict__ sb,
                                               const float* __restrict__ sc,
                                               const float* __restrict__ sd,
                                               float* __restrict__ out) {
    __shared__ float red[256];
    int q = blockIdx.x, tid = threadIdx.x;
    float v = desc[q * 256 + tid];
    red[tid] = v; __syncthreads();
    for (int st = 128; st > 0; st >>= 1) {
        if (tid < st) red[tid] += red[tid + st];
        __syncthreads();
    }
    float mean = red[0] * (1.f / 256.f);
    __syncthreads();
    float dv = v - mean;
    red[tid] = dv * dv; __syncthreads();
    for (int st = 128; st > 0; st >>= 1) {
        if (tid < st) red[tid] += red[tid + st];
        __syncthreads();
    }
    float var = red[0] * (1.f / 255.f);
    float norm = dv / (sqrtf(var) + 1e-6f);
    float dx = qloc[q * 2]     - ploc[tid * 2];
    float dy = qloc[q * 2 + 1] - ploc[tid * 2 + 1];
    float dist = sqrtf(dx * dx + dy * dy);
    float z = sa[0] * norm + sb[0];
    float sig = 1.f / (1.f + expf(-z));
    out[q * 256 + tid] = (sc[0] - sig) * (-logf(dist + 1.f) - sd[0]);
}

extern "C" void kernel_launch(void* const* d_in, const int* in_sizes, int n_in,
                              void* d_out, int out_size, void* d_ws, size_t ws_size,
                              hipStream_t stream) {
    const float* qx   = (const float*)d_in[0];
    const float* qloc = (const float*)d_in[1];
    const float* px   = (const float*)d_in[2];
    const float* ploc = (const float*)d_in[3];
    const float* encw = (const float*)d_in[4];
    const float* cw1  = (const float*)d_in[5];
    const float* cb1  = (const float*)d_in[6];
    const float* cw2  = (const float*)d_in[7];
    const float* cb2  = (const float*)d_in[8];
    const float* cw3  = (const float*)d_in[9];
    const float* cb3  = (const float*)d_in[10];
    const float* dw1  = (const float*)d_in[11];
    const float* db1  = (const float*)d_in[12];
    const float* dw2  = (const float*)d_in[13];
    const float* db2  = (const float*)d_in[14];
    const float* dw3  = (const float*)d_in[15];
    const float* sa   = (const float*)d_in[16];
    const float* sb   = (const float*)d_in[17];
    const float* sc   = (const float*)d_in[18];
    const float* sd   = (const float*)d_in[19];

    char* w = (char*)d_ws;
    unsigned*       wtp     = (unsigned*)w;       w += (size_t)8193 * 128 * 4;      // 4.19 MB
    float*          encoded = (float*)w;          w += (size_t)NB * LTOK * H1 * 4;  // 4.5 MB
    unsigned short* xbuf    = (unsigned short*)w; w += (size_t)NB * LTOK * H1 * 2;  // 2.25 MB
    unsigned short* act1    = (unsigned short*)w; w += (size_t)NB * LTOK * H1 * 2;
    unsigned short* act2    = (unsigned short*)w; w += (size_t)NB * LTOK * H1 * 2;
    float*          actF    = (float*)w;          w += (size_t)NB * LTOK * H1 * 4;
    unsigned short* wtb     = (unsigned short*)w; w += (size_t)3 * 256 * 1280 * 2;  // 1.97 MB
    int*            idxl    = (int*)w;            w += (size_t)NB * LTOK * IDXCAP * 4; // 3.83 MB
    int*            cnts    = (int*)w;            w += (size_t)NB * LTOK * 4;
    float*          Cmat    = (float*)w;          w += (size_t)NB * H2 * 4;
    unsigned*       masks   = (unsigned*)w;       w += (size_t)NB * MASKW * 4;
    float*          qbits   = (float*)w;          w += 1024;
    float*          desc    = (float*)w;          w += (size_t)NBQ * NBP * 4;

    hipMemsetAsync(masks, 0, (size_t)NB * MASKW * 4, stream);
    k_transpose_pack<<<dim3(CIN / 32, H1 / 32), 256, 0, stream>>>(encw, wtp);
    k_wprep<<<3840, 256, 0, stream>>>(cw1, cw2, cw3, wtb, wtp);
    k_scan<<<NB * LTOK, 256, 0, stream>>>(qx, px, idxl, cnts, masks);
    k_gather<<<NB * LTOK, 128, 0, stream>>>(wtp, idxl, cnts, encoded, (unsigned*)xbuf);
    k_qbits<<<NBQ, 256, 0, stream>>>(masks, qbits);
    dim3 cgrid(NB * LTOK / 32, 8);
    k_cgemm<<<cgrid, 256, 0, stream>>>(xbuf, act1, actF, wtb,              cb1, 0);
    k_cgemm<<<cgrid, 256, 0, stream>>>(act1, act2, actF, wtb + 327680,     cb2, 0);
    k_cgemm<<<cgrid, 256, 0, stream>>>(act2, act1, actF, wtb + 2 * 327680, cb3, 1);
    k_ab<<<NB, 256, 0, stream>>>(actF, encoded, dw1, Cmat);
    k_pair<<<dim3(NBP, NBQ), 256, 0, stream>>>(Cmat, db1, dw2, db2, dw3, masks, qbits, desc);
    k_final<<<NBQ, 256, 0, stream>>>(desc, qloc, ploc, sa, sb, sc, sd, (float*)d_out);
}

// Round 5
// 351.182 us; speedup vs baseline: 1.6713x; 1.0228x over previous
//
#include <hip/hip_runtime.h>

#define NB 288          // 32 query + 256 poi batches
#define NBQ 32
#define NBP 256
#define LTOK 16
#define CIN 8192
#define H1 256
#define H2 32
#define MASKW 256       // 8192 bits / 32
#define XROW 264        // padded LDS row stride (bf16 elems)
#define IDXCAP 208      // idx-list slots per row (mean 82, huge margin, 16B aligned)

typedef __attribute__((ext_vector_type(8))) short short8;   // 8 bf16 = 4 VGPRs
typedef __attribute__((ext_vector_type(4))) float f32x4;

__device__ __forceinline__ unsigned short f2bf(float f) {
    unsigned u = __float_as_uint(f);
    u += 0x7fffu + ((u >> 16) & 1u);
    return (unsigned short)(u >> 16);
}

// enc_w (256,8192) fp32 -> wtp[k][pair] packed 2xbf16 (ch 2p low, 2p+1 high)
__global__ __launch_bounds__(256) void k_transpose_pack(const float* __restrict__ w,
                                                        unsigned* __restrict__ wtp) {
    __shared__ float tile[32][33];
    int k0 = blockIdx.x * 32;          // along 8192
    int h0 = blockIdx.y * 32;          // along 256
    int tx = threadIdx.x & 31, ty = threadIdx.x >> 5;
#pragma unroll
    for (int i = 0; i < 32; i += 8)
        tile[ty + i][tx] = w[(h0 + ty + i) * CIN + k0 + tx];   // tile[h_local][k_local]
    __syncthreads();
    int kl = threadIdx.x >> 3, pw = threadIdx.x & 7;
#pragma unroll
    for (int u = 0; u < 2; ++u) {
        int p = pw + u * 8;            // pair within h-tile, 0..15
        unsigned lo = f2bf(tile[2 * p][kl]);
        unsigned hi = f2bf(tile[2 * p + 1][kl]);
        wtp[(size_t)(k0 + kl) * 128 + (h0 >> 1) + p] = (hi << 16) | lo;
    }
}

// conv weights w[o][i][d] fp32 -> WT bf16 [l][o][d][i]; also zero wtp sentinel row
__global__ __launch_bounds__(256) void k_wprep(const float* __restrict__ w1,
                                               const float* __restrict__ w2,
                                               const float* __restrict__ w3,
                                               unsigned short* __restrict__ wtb,
                                               unsigned* __restrict__ wtp) {
    int bx = blockIdx.x;                 // 0..3839 = l*1280 + o*5 + d
    if (bx == 0 && threadIdx.x < 128) wtp[(size_t)8192 * 128 + threadIdx.x] = 0;  // sentinel
    int l = bx / 1280;
    int r = bx - l * 1280;
    int o = r / 5;
    int d = r - o * 5;
    int i = threadIdx.x;
    const float* w = (l == 0) ? w1 : (l == 1) ? w2 : w3;
    wtb[(size_t)l * 327680 + (size_t)o * 1280 + d * 256 + i] =
        f2bf(w[(size_t)o * 1280 + i * 5 + d]);
}

// dec_w3 (8192 x 32) fp32 -> w3p[k][16] packed bf16 pairs
__global__ __launch_bounds__(256) void k_w3pack(const float* __restrict__ w3,
                                                unsigned* __restrict__ w3p) {
    int idx = blockIdx.x * 256 + threadIdx.x;   // 0..131071
    int k = idx >> 4, pw = idx & 15;
    unsigned lo = f2bf(w3[k * 32 + 2 * pw]);
    unsigned hi = f2bf(w3[k * 32 + 2 * pw + 1]);
    w3p[idx] = (hi << 16) | lo;
}

// Pure HBM scan, MLP=8: all loads issued before any processing
__global__ __launch_bounds__(256) void k_scan(const float* __restrict__ qx,
                                              const float* __restrict__ px,
                                              int* __restrict__ idxl,
                                              int* __restrict__ cnts,
                                              unsigned* __restrict__ masks) {
    int row = blockIdx.x;              // 0..4607
    int b = row >> 4;
    const float* x = (b < NBQ) ? (qx + (size_t)row * CIN)
                               : (px + (size_t)(row - NBQ * LTOK) * CIN);
    __shared__ int cnt;
    int tid = threadIdx.x;
    if (tid == 0) cnt = 0;
    __syncthreads();
    const float4* x4 = (const float4*)x;
    float4 r[8];
#pragma unroll
    for (int j = 0; j < 8; ++j) r[j] = x4[j * 256 + tid];   // 8 outstanding 1KB loads
    int* il = idxl + (size_t)row * IDXCAP;
#pragma unroll
    for (int j = 0; j < 8; ++j) {
        unsigned ox = __float_as_uint(r[j].x) | __float_as_uint(r[j].y) |
                      __float_as_uint(r[j].z) | __float_as_uint(r[j].w);
        if (ox) {
            int base = (j * 256 + tid) * 4;
            float vv[4] = {r[j].x, r[j].y, r[j].z, r[j].w};
#pragma unroll
            for (int c = 0; c < 4; ++c) {
                if (vv[c] != 0.f) {
                    int k = base + c;
                    int p = atomicAdd(&cnt, 1);
                    if (p < 192) il[p] = k;
                    atomicOr(&masks[b * MASKW + (k >> 5)], 1u << (k & 31));
                }
            }
        }
    }
    __syncthreads();
    int n = min(cnt, 192);
    if (tid == 0) cnts[row] = n;
    for (int i = n + tid; i < 200; i += 256) il[i] = 8192;   // sentinel pad
}

// Gather: 1 row/block, 128 threads = channel pairs; bf16 packed table, unroll 8
__global__ __launch_bounds__(128) void k_gather(const unsigned* __restrict__ wtp,
                                                const int* __restrict__ idxl,
                                                const int* __restrict__ cnts,
                                                float* __restrict__ encoded,
                                                unsigned* __restrict__ xbufu) {
    int row = blockIdx.x, tid = threadIdx.x;
    int n = cnts[row];
    const int* il = idxl + (size_t)row * IDXCAP;
    float aL = 0.f, aH = 0.f;
    for (int j = 0; j < n; j += 8) {
        int4 ia = *(const int4*)(il + j);
        int4 ib = *(const int4*)(il + j + 4);
        int id[8] = {ia.x, ia.y, ia.z, ia.w, ib.x, ib.y, ib.z, ib.w};
#pragma unroll
        for (int u = 0; u < 8; ++u) {
            unsigned v = wtp[(size_t)id[u] * 128 + tid];
            aL += __uint_as_float(v << 16);
            aH += __uint_as_float(v & 0xffff0000u);
        }
    }
    ((float2*)encoded)[(size_t)row * 128 + tid] = float2{aL, aH};
    unsigned bl = f2bf(aL), bh = f2bf(aH);
    xbufu[(size_t)row * 128 + tid] = (bh << 16) | bl;
}

// Conv layer GEMM, 32 rows (2 batches) x 32 outs per block, grid (144,8).
__global__ __launch_bounds__(256) void k_cgemm(const unsigned short* __restrict__ actIn,
                                               unsigned short* __restrict__ actOut,
                                               float* __restrict__ actOutF,
                                               const unsigned short* __restrict__ wl,
                                               const float* __restrict__ bias,
                                               int last) {
    __shared__ unsigned short Als[2 * 20 * XROW];   // 21.1 KB
    __shared__ unsigned short Bls[32 * XROW];       // 16.9 KB
    int tid = threadIdx.x;
    int m0 = blockIdx.x * 32, n0 = blockIdx.y * 32;

    int* Ai = (int*)Als;
#pragma unroll
    for (int i = tid; i < 20 * XROW; i += 256) Ai[i] = 0;
    __syncthreads();

    int row = tid >> 3, part = tid & 7;       // 32 rows, 64B per thread
    {
        const short8* src = (const short8*)(actIn + (size_t)(m0 + row) * 256 + part * 32);
        unsigned short* dst = Als + ((row >> 4) * 20 + (row & 15) + 2) * XROW + part * 32;
#pragma unroll
        for (int j = 0; j < 4; ++j) *(short8*)(dst + j * 8) = src[j];
    }
    const unsigned short* bsrc = wl + (size_t)(n0 + row) * 1280 + part * 32;
    short8 rb[4];
#pragma unroll
    for (int j = 0; j < 4; ++j) rb[j] = *(const short8*)(bsrc + j * 8);

    int lane = tid & 63, wave = tid >> 6;
    int lane15 = lane & 15, quad = lane >> 4;
    int wm = wave & 1, wn = wave >> 1;
    unsigned short* bdst = Bls + row * XROW + part * 32;

    f32x4 acc = (f32x4){0.f, 0.f, 0.f, 0.f};

#pragma unroll 1
    for (int d = 0; d < 5; ++d) {
#pragma unroll
        for (int j = 0; j < 4; ++j) *(short8*)(bdst + j * 8) = rb[j];
        __syncthreads();
        if (d < 4) {
            const unsigned short* s2 = bsrc + (d + 1) * 256;
#pragma unroll
            for (int j = 0; j < 4; ++j) rb[j] = *(const short8*)(s2 + j * 8);
        }
        const unsigned short* ap = Als + (wm * 20 + lane15 + d) * XROW + quad * 8;
        const unsigned short* bp = Bls + (wn * 16 + lane15) * XROW + quad * 8;
#pragma unroll
        for (int kk = 0; kk < 8; ++kk) {
            short8 av = *(const short8*)(ap + kk * 32);
            short8 bv = *(const short8*)(bp + kk * 32);
            acc = __builtin_amdgcn_mfma_f32_16x16x32_bf16(av, bv, acc, 0, 0, 0);
        }
        __syncthreads();
    }

    int o = n0 + wn * 16 + lane15;
    float bv = bias[o];
    int rbase = m0 + wm * 16 + quad * 4;
#pragma unroll
    for (int r = 0; r < 4; ++r) {
        float v = fmaxf(acc[r] + bv, 0.f);
        if (last) actOutF[(size_t)(rbase + r) * 256 + o] = v;
        else      actOut[(size_t)(rbase + r) * 256 + o] = f2bf(v);
    }
}

// e = relu((sum_t conv3 + sum_t encoded)/16); Cmat[b][o] = dec_w1 half . e
__global__ __launch_bounds__(256) void k_ab(const float* __restrict__ actF,
                                            const float* __restrict__ encoded,
                                            const float* __restrict__ w1,
                                            float* __restrict__ Cmat) {
    int b = blockIdx.x, tid = threadIdx.x;
    __shared__ float e[256];
    __shared__ float red[256];
    float s = 0.f;
#pragma unroll
    for (int t = 0; t < 16; ++t)
        s += actF[((size_t)b * 16 + t) * 256 + tid] + encoded[((size_t)b * 16 + t) * 256 + tid];
    e[tid] = fmaxf(s * (1.f / 16.f), 0.f);
    __syncthreads();
    int o = tid & 31, seg = tid >> 5;
    const float* wr = w1 + (size_t)o * 512 + (b < NBQ ? 0 : 256) + seg * 32;
    float v = 0.f;
#pragma unroll
    for (int i = 0; i < 32; ++i) v = fmaf(wr[i], e[seg * 32 + i], v);
    red[tid] = v; __syncthreads();
    if (tid < 128) red[tid] += red[tid + 128]; __syncthreads();
    if (tid < 64)  red[tid] += red[tid + 64];  __syncthreads();
    if (tid < 32) {
        red[tid] += red[tid + 32];
        Cmat[b * 32 + tid] = red[tid];
    }
}

// One block per (q,p): tiny MLP + compacted sparse decode (bf16 w3, 4 lanes/row)
// qbits fused: popcount of q-mask reduced in-block.
__global__ __launch_bounds__(256) void k_pair(const float* __restrict__ Cmat,
                                              const float* __restrict__ b1,
                                              const float* __restrict__ w2,
                                              const float* __restrict__ b2,
                                              const unsigned* __restrict__ w3p,
                                              const unsigned* __restrict__ masks,
                                              float* __restrict__ desc) {
    int p = blockIdx.x, q = blockIdx.y;
    __shared__ float h1[32];
    __shared__ __align__(16) float h2s[32];
    __shared__ int idxs[3072];
    __shared__ int cnt;
    __shared__ float wsum[4], wq[4];
    int tid = threadIdx.x;
    if (tid == 0) cnt = 0;
    __syncthreads();
    unsigned mq = masks[q * MASKW + tid];
    unsigned m = mq & masks[(NBQ + p) * MASKW + tid];
    int nb = __popc(m);
    if (nb) {
        int pos = atomicAdd(&cnt, nb);
        while (m) {
            int bit = __ffs(m) - 1;
            m &= m - 1;
            idxs[pos++] = tid * 32 + bit;
        }
    }
    if (tid < 32)
        h1[tid] = fmaxf(Cmat[q * 32 + tid] + Cmat[(NBQ + p) * 32 + tid] + b1[tid], 0.f);
    __syncthreads();
    if (tid < 32) {
        float s = b2[tid];
#pragma unroll
        for (int j = 0; j < 32; ++j) s = fmaf(w2[tid * 32 + j], h1[j], s);
        h2s[tid] = fmaxf(s, 0.f);
    }
    __syncthreads();
    int n = cnt;
    int rowi = tid >> 2, part = tid & 3;          // 64 rows/iter, 4 lanes/row
    float h2v[8];
#pragma unroll
    for (int j = 0; j < 8; ++j) h2v[j] = h2s[part * 8 + j];
    float local = 0.f;
    for (int base = 0; base < n; base += 64) {
        int r = base + rowi;
        bool act = r < n;
        float dot = 0.f;
        if (act) {
            uint4 wv = *(const uint4*)(w3p + (size_t)idxs[r] * 16 + part * 4);
            unsigned wu[4] = {wv.x, wv.y, wv.z, wv.w};
#pragma unroll
            for (int u = 0; u < 4; ++u) {
                dot += __uint_as_float(wu[u] << 16) * h2v[2 * u];
                dot += __uint_as_float(wu[u] & 0xffff0000u) * h2v[2 * u + 1];
            }
        }
        dot += __shfl_xor(dot, 1);
        dot += __shfl_xor(dot, 2);
        if (act && part == 0)
            local += 1.f + (dot >= 0.f ? dot : dot * 0.125f);
    }
    float qcf = (float)__popc(mq);
#pragma unroll
    for (int st = 1; st < 64; st <<= 1) {
        local += __shfl_xor(local, st);
        qcf   += __shfl_xor(qcf, st);
    }
    if ((tid & 63) == 0) { wsum[tid >> 6] = local; wq[tid >> 6] = qcf; }
    __syncthreads();
    if (tid == 0) {
        float t  = wsum[0] + wsum[1] + wsum[2] + wsum[3];
        float qb = wq[0] + wq[1] + wq[2] + wq[3];
        desc[q * 256 + p] = t / qb;
    }
}

// One block per q row: normalize over p, fuse geo distance
__global__ __launch_bounds__(256) void k_final(const float* __restrict__ desc,
                                               const float* __restrict__ qloc,
                                               const float* __restrict__ ploc,
                                               const float* __restrict__ sa,
                                               const float* __restrict__ sb,
                                               const float* __restrict__ sc,
                                               const float* __restrict__ sd,
                                               float* __restrict__ out) {
    __shared__ float red[256];
    int q = blockIdx.x, tid = threadIdx.x;
    float v = desc[q * 256 + tid];
    red[tid] = v; __syncthreads();
    for (int st = 128; st > 0; st >>= 1) {
        if (tid < st) red[tid] += red[tid + st];
        __syncthreads();
    }
    float mean = red[0] * (1.f / 256.f);
    __syncthreads();
    float dv = v - mean;
    red[tid] = dv * dv; __syncthreads();
    for (int st = 128; st > 0; st >>= 1) {
        if (tid < st) red[tid] += red[tid + st];
        __syncthreads();
    }
    float var = red[0] * (1.f / 255.f);
    float norm = dv / (sqrtf(var) + 1e-6f);
    float dx = qloc[q * 2]     - ploc[tid * 2];
    float dy = qloc[q * 2 + 1] - ploc[tid * 2 + 1];
    float dist = sqrtf(dx * dx + dy * dy);
    float z = sa[0] * norm + sb[0];
    float sig = 1.f / (1.f + expf(-z));
    out[q * 256 + tid] = (sc[0] - sig) * (-logf(dist + 1.f) - sd[0]);
}

extern "C" void kernel_launch(void* const* d_in, const int* in_sizes, int n_in,
                              void* d_out, int out_size, void* d_ws, size_t ws_size,
                              hipStream_t stream) {
    const float* qx   = (const float*)d_in[0];
    const float* qloc = (const float*)d_in[1];
    const float* px   = (const float*)d_in[2];
    const float* ploc = (const float*)d_in[3];
    const float* encw = (const float*)d_in[4];
    const float* cw1  = (const float*)d_in[5];
    const float* cb1  = (const float*)d_in[6];
    const float* cw2  = (const float*)d_in[7];
    const float* cb2  = (const float*)d_in[8];
    const float* cw3  = (const float*)d_in[9];
    const float* cb3  = (const float*)d_in[10];
    const float* dw1  = (const float*)d_in[11];
    const float* db1  = (const float*)d_in[12];
    const float* dw2  = (const float*)d_in[13];
    const float* db2  = (const float*)d_in[14];
    const float* dw3  = (const float*)d_in[15];
    const float* sa   = (const float*)d_in[16];
    const float* sb   = (const float*)d_in[17];
    const float* sc   = (const float*)d_in[18];
    const float* sd   = (const float*)d_in[19];

    char* w = (char*)d_ws;
    unsigned*       wtp     = (unsigned*)w;       w += (size_t)8193 * 128 * 4;      // 4.19 MB
    float*          encoded = (float*)w;          w += (size_t)NB * LTOK * H1 * 4;  // 4.5 MB
    unsigned short* xbuf    = (unsigned short*)w; w += (size_t)NB * LTOK * H1 * 2;  // 2.25 MB
    unsigned short* act1    = (unsigned short*)w; w += (size_t)NB * LTOK * H1 * 2;
    unsigned short* act2    = (unsigned short*)w; w += (size_t)NB * LTOK * H1 * 2;
    float*          actF    = (float*)w;          w += (size_t)NB * LTOK * H1 * 4;
    unsigned short* wtb     = (unsigned short*)w; w += (size_t)3 * 256 * 1280 * 2;  // 1.97 MB
    unsigned*       w3p     = (unsigned*)w;       w += (size_t)CIN * 16 * 4;        // 512 KB
    int*            idxl    = (int*)w;            w += (size_t)NB * LTOK * IDXCAP * 4;
    int*            cnts    = (int*)w;            w += (size_t)NB * LTOK * 4;
    float*          Cmat    = (float*)w;          w += (size_t)NB * H2 * 4;
    unsigned*       masks   = (unsigned*)w;       w += (size_t)NB * MASKW * 4;
    float*          desc    = (float*)w;          w += (size_t)NBQ * NBP * 4;

    hipMemsetAsync(masks, 0, (size_t)NB * MASKW * 4, stream);
    k_transpose_pack<<<dim3(CIN / 32, H1 / 32), 256, 0, stream>>>(encw, wtp);
    k_wprep<<<3840, 256, 0, stream>>>(cw1, cw2, cw3, wtb, wtp);
    k_w3pack<<<512, 256, 0, stream>>>(dw3, w3p);
    k_scan<<<NB * LTOK, 256, 0, stream>>>(qx, px, idxl, cnts, masks);
    k_gather<<<NB * LTOK, 128, 0, stream>>>(wtp, idxl, cnts, encoded, (unsigned*)xbuf);
    dim3 cgrid(NB * LTOK / 32, 8);
    k_cgemm<<<cgrid, 256, 0, stream>>>(xbuf, act1, actF, wtb,              cb1, 0);
    k_cgemm<<<cgrid, 256, 0, stream>>>(act1, act2, actF, wtb + 327680,     cb2, 0);
    k_cgemm<<<cgrid, 256, 0, stream>>>(act2, act1, actF, wtb + 2 * 327680, cb3, 1);
    k_ab<<<NB, 256, 0, stream>>>(actF, encoded, dw1, Cmat);
    k_pair<<<dim3(NBP, NBQ), 256, 0, stream>>>(Cmat, db1, dw2, db2, w3p, masks, desc);
    k_final<<<NBQ, 256, 0, stream>>>(desc, qloc, ploc, sa, sb, sc, sd, (float*)d_out);
}

// Round 6
// 335.649 us; speedup vs baseline: 1.7486x; 1.0463x over previous
//
#include <hip/hip_runtime.h>

#define NB 288          // 32 query + 256 poi batches
#define NBQ 32
#define NBP 256
#define LTOK 16
#define CIN 8192
#define H1 256
#define H2 32
#define MASKW 256       // 8192 bits / 32
#define XROW 264        // padded LDS row stride (bf16 elems)

typedef __attribute__((ext_vector_type(8))) short short8;   // 8 bf16 = 4 VGPRs
typedef __attribute__((ext_vector_type(4))) float f32x4;

__device__ __forceinline__ unsigned short f2bf(float f) {
    unsigned u = __float_as_uint(f);
    u += 0x7fffu + ((u >> 16) & 1u);
    return (unsigned short)(u >> 16);
}

// ---------------- fused prep: enc_w transpose-pack, conv-w prep, w3 pack,
// ---------------- zero masks/esum/Cmat + wtp sentinel row ----------------
__global__ __launch_bounds__(256) void k_prep(const float* __restrict__ encw,
                                              const float* __restrict__ w1,
                                              const float* __restrict__ w2,
                                              const float* __restrict__ w3c,
                                              const float* __restrict__ dw3,
                                              unsigned* __restrict__ wtp,
                                              unsigned short* __restrict__ wtb,
                                              unsigned* __restrict__ w3p,
                                              unsigned* __restrict__ masks,
                                              float* __restrict__ esum,
                                              float* __restrict__ Cmat) {
    int g = blockIdx.x, tid = threadIdx.x;
    if (g < 2048) {
        // enc_w (256,8192) fp32 -> wtp[k][pair] packed 2xbf16
        __shared__ float tile[32][33];
        int k0 = (g >> 3) * 32, h0 = (g & 7) * 32;
        int tx = tid & 31, ty = tid >> 5;
#pragma unroll
        for (int i = 0; i < 32; i += 8)
            tile[ty + i][tx] = encw[(h0 + ty + i) * CIN + k0 + tx];
        __syncthreads();
        int kl = tid >> 3, pw = tid & 7;
#pragma unroll
        for (int u = 0; u < 2; ++u) {
            int p = pw + u * 8;
            unsigned lo = f2bf(tile[2 * p][kl]);
            unsigned hi = f2bf(tile[2 * p + 1][kl]);
            wtp[(size_t)(k0 + kl) * 128 + (h0 >> 1) + p] = (hi << 16) | lo;
        }
    } else if (g < 5888) {
        // conv weights w[o][i][d] fp32 -> WT bf16 [l][o][d][i]
        int bx = g - 2048;
        int l = bx / 1280;
        int r = bx - l * 1280;
        int o = r / 5;
        int d = r - o * 5;
        const float* w = (l == 0) ? w1 : (l == 1) ? w2 : w3c;
        wtb[(size_t)l * 327680 + (size_t)o * 1280 + d * 256 + tid] =
            f2bf(w[(size_t)o * 1280 + tid * 5 + d]);
    } else if (g < 6400) {
        // dec_w3 (8192 x 32) fp32 -> w3p[k][16] packed bf16 pairs
        int idx = (g - 5888) * 256 + tid;
        int k = idx >> 4, pw = idx & 15;
        unsigned lo = f2bf(dw3[k * 32 + 2 * pw]);
        unsigned hi = f2bf(dw3[k * 32 + 2 * pw + 1]);
        w3p[idx] = (hi << 16) | lo;
    } else {
        int b = g - 6400;                 // 0..287
        masks[b * MASKW + tid] = 0u;
        esum[b * 256 + tid] = 0.f;
        if (tid < 32) Cmat[b * 32 + tid] = 0.f;
        if (b == 0 && tid < 128) wtp[(size_t)8192 * 128 + tid] = 0u;  // sentinel
    }
}

// ---------------- fused scan + gather: one block per (batch,token) row ----
__global__ __launch_bounds__(256) void k_scanG(const float* __restrict__ qx,
                                               const float* __restrict__ px,
                                               const unsigned* __restrict__ wtp,
                                               unsigned* __restrict__ masks,
                                               float* __restrict__ esum,
                                               unsigned* __restrict__ xbufu) {
    int row = blockIdx.x;              // 0..4607
    int b = row >> 4;
    const float* x = (b < NBQ) ? (qx + (size_t)row * CIN)
                               : (px + (size_t)(row - NBQ * LTOK) * CIN);
    __shared__ int idxs[200];
    __shared__ int cnt;
    __shared__ float sL[2][128], sH[2][128];
    int tid = threadIdx.x;
    if (tid == 0) cnt = 0;
    __syncthreads();
    const float4* x4 = (const float4*)x;
    float4 r[8];
#pragma unroll
    for (int j = 0; j < 8; ++j) r[j] = x4[j * 256 + tid];   // 8 outstanding loads
#pragma unroll
    for (int j = 0; j < 8; ++j) {
        unsigned ox = __float_as_uint(r[j].x) | __float_as_uint(r[j].y) |
                      __float_as_uint(r[j].z) | __float_as_uint(r[j].w);
        if (ox) {
            int base = (j * 256 + tid) * 4;
            float vv[4] = {r[j].x, r[j].y, r[j].z, r[j].w};
#pragma unroll
            for (int c = 0; c < 4; ++c) {
                if (vv[c] != 0.f) {
                    int k = base + c;
                    int p = atomicAdd(&cnt, 1);
                    if (p < 192) idxs[p] = k;
                    atomicOr(&masks[b * MASKW + (k >> 5)], 1u << (k & 31));
                }
            }
        }
    }
    __syncthreads();
    int n = min(cnt, 192);
    for (int i = n + tid; i < 200; i += 256) idxs[i] = 8192;   // sentinel pad
    __syncthreads();
    // gather: 128 channel-pairs x 2 j-halves
    int pair = tid & 127, half = tid >> 7;
    float aL = 0.f, aH = 0.f;
    for (int j0 = 0; j0 < n; j0 += 8) {
        int4 ia = *(const int4*)(idxs + j0 + half * 4);
        int id[4] = {ia.x, ia.y, ia.z, ia.w};
#pragma unroll
        for (int u = 0; u < 4; ++u) {
            unsigned v = wtp[(size_t)id[u] * 128 + pair];
            aL += __uint_as_float(v << 16);
            aH += __uint_as_float(v & 0xffff0000u);
        }
    }
    sL[half][pair] = aL; sH[half][pair] = aH;
    __syncthreads();
    if (tid < 128) {
        float L = sL[0][tid] + sL[1][tid];
        float H = sH[0][tid] + sH[1][tid];
        atomicAdd(&esum[b * 256 + 2 * tid],     L);
        atomicAdd(&esum[b * 256 + 2 * tid + 1], H);
        unsigned bl = f2bf(L), bh = f2bf(H);
        xbufu[(size_t)row * 128 + tid] = (bh << 16) | bl;
    }
}

// ---------------- conv layer GEMM (layers 1,2): 32 rows x 32 outs ---------
__global__ __launch_bounds__(256) void k_cgemm(const unsigned short* __restrict__ actIn,
                                               unsigned short* __restrict__ actOut,
                                               const unsigned short* __restrict__ wl,
                                               const float* __restrict__ bias) {
    __shared__ unsigned short Als[2 * 20 * XROW];   // 21.1 KB
    __shared__ unsigned short Bls[32 * XROW];       // 16.9 KB
    int tid = threadIdx.x;
    int m0 = blockIdx.x * 32, n0 = blockIdx.y * 32;

    int* Ai = (int*)Als;
#pragma unroll
    for (int i = tid; i < 20 * XROW; i += 256) Ai[i] = 0;
    __syncthreads();

    int row = tid >> 3, part = tid & 7;
    {
        const short8* src = (const short8*)(actIn + (size_t)(m0 + row) * 256 + part * 32);
        unsigned short* dst = Als + ((row >> 4) * 20 + (row & 15) + 2) * XROW + part * 32;
#pragma unroll
        for (int j = 0; j < 4; ++j) *(short8*)(dst + j * 8) = src[j];
    }
    const unsigned short* bsrc = wl + (size_t)(n0 + row) * 1280 + part * 32;
    short8 rb[4];
#pragma unroll
    for (int j = 0; j < 4; ++j) rb[j] = *(const short8*)(bsrc + j * 8);

    int lane = tid & 63, wave = tid >> 6;
    int lane15 = lane & 15, quad = lane >> 4;
    int wm = wave & 1, wn = wave >> 1;
    unsigned short* bdst = Bls + row * XROW + part * 32;

    f32x4 acc = (f32x4){0.f, 0.f, 0.f, 0.f};
#pragma unroll 1
    for (int d = 0; d < 5; ++d) {
#pragma unroll
        for (int j = 0; j < 4; ++j) *(short8*)(bdst + j * 8) = rb[j];
        __syncthreads();
        if (d < 4) {
            const unsigned short* s2 = bsrc + (d + 1) * 256;
#pragma unroll
            for (int j = 0; j < 4; ++j) rb[j] = *(const short8*)(s2 + j * 8);
        }
        const unsigned short* ap = Als + (wm * 20 + lane15 + d) * XROW + quad * 8;
        const unsigned short* bp = Bls + (wn * 16 + lane15) * XROW + quad * 8;
#pragma unroll
        for (int kk = 0; kk < 8; ++kk) {
            short8 av = *(const short8*)(ap + kk * 32);
            short8 bv = *(const short8*)(bp + kk * 32);
            acc = __builtin_amdgcn_mfma_f32_16x16x32_bf16(av, bv, acc, 0, 0, 0);
        }
        __syncthreads();
    }

    int o = n0 + wn * 16 + lane15;
    float bv = bias[o];
    int rbase = m0 + wm * 16 + quad * 4;
#pragma unroll
    for (int r = 0; r < 4; ++r)
        actOut[(size_t)(rbase + r) * 256 + o] = f2bf(fmaxf(acc[r] + bv, 0.f));
}

// ---------------- conv layer 3 + fused mean/residual/relu + dec_w1 matvec --
__global__ __launch_bounds__(256) void k_cgemm3(const unsigned short* __restrict__ actIn,
                                                const unsigned short* __restrict__ wl,
                                                const float* __restrict__ bias,
                                                const float* __restrict__ esum,
                                                const float* __restrict__ dw1,
                                                float* __restrict__ Cmat) {
    __shared__ unsigned short Als[2 * 20 * XROW];
    __shared__ unsigned short Bls[32 * XROW];
    __shared__ float els[2][32];
    int tid = threadIdx.x;
    int m0 = blockIdx.x * 32, n0 = blockIdx.y * 32;

    int* Ai = (int*)Als;
#pragma unroll
    for (int i = tid; i < 20 * XROW; i += 256) Ai[i] = 0;
    __syncthreads();

    int row = tid >> 3, part = tid & 7;
    {
        const short8* src = (const short8*)(actIn + (size_t)(m0 + row) * 256 + part * 32);
        unsigned short* dst = Als + ((row >> 4) * 20 + (row & 15) + 2) * XROW + part * 32;
#pragma unroll
        for (int j = 0; j < 4; ++j) *(short8*)(dst + j * 8) = src[j];
    }
    const unsigned short* bsrc = wl + (size_t)(n0 + row) * 1280 + part * 32;
    short8 rb[4];
#pragma unroll
    for (int j = 0; j < 4; ++j) rb[j] = *(const short8*)(bsrc + j * 8);

    int lane = tid & 63, wave = tid >> 6;
    int lane15 = lane & 15, quad = lane >> 4;
    int wm = wave & 1, wn = wave >> 1;
    unsigned short* bdst = Bls + row * XROW + part * 32;

    f32x4 acc = (f32x4){0.f, 0.f, 0.f, 0.f};
#pragma unroll 1
    for (int d = 0; d < 5; ++d) {
#pragma unroll
        for (int j = 0; j < 4; ++j) *(short8*)(bdst + j * 8) = rb[j];
        __syncthreads();
        if (d < 4) {
            const unsigned short* s2 = bsrc + (d + 1) * 256;
#pragma unroll
            for (int j = 0; j < 4; ++j) rb[j] = *(const short8*)(s2 + j * 8);
        }
        const unsigned short* ap = Als + (wm * 20 + lane15 + d) * XROW + quad * 8;
        const unsigned short* bp = Bls + (wn * 16 + lane15) * XROW + quad * 8;
#pragma unroll
        for (int kk = 0; kk < 8; ++kk) {
            short8 av = *(const short8*)(ap + kk * 32);
            short8 bv = *(const short8*)(bp + kk * 32);
            acc = __builtin_amdgcn_mfma_f32_16x16x32_bf16(av, bv, acc, 0, 0, 0);
        }
        __syncthreads();
    }

    // token-mean of relu(conv3) + residual mean + relu -> e tile (2 batches x 32 outs)
    int o_l = wn * 16 + lane15;
    int o = n0 + o_l;
    float bv = bias[o];
    float sf = 0.f;
#pragma unroll
    for (int r = 0; r < 4; ++r) sf += fmaxf(acc[r] + bv, 0.f);
    sf += __shfl_xor(sf, 16, 64);
    sf += __shfl_xor(sf, 32, 64);
    if (quad == 0) {
        int bb = 2 * blockIdx.x + wm;
        els[wm][o_l] = fmaxf((sf + esum[bb * 256 + o]) * (1.f / 16.f), 0.f);
    }
    __syncthreads();
    // partial Cmat[b][o'] += sum_{o in tile} dec_w1[o'][off + o] * e[b][o]
    if (tid < 64) {
        int b2 = tid >> 5, op = tid & 31;
        int bb = 2 * blockIdx.x + b2;
        const float* wr = dw1 + (size_t)op * 512 + (bb < NBQ ? 0 : 256) + n0;
        float s = 0.f;
#pragma unroll
        for (int j = 0; j < 32; ++j) s = fmaf(wr[j], els[b2][j], s);
        atomicAdd(&Cmat[bb * 32 + op], s);
    }
}

// ---------------- per-(q,p): tiny MLP + compacted sparse decode -----------
__global__ __launch_bounds__(256) void k_pair(const float* __restrict__ Cmat,
                                              const float* __restrict__ b1,
                                              const float* __restrict__ w2,
                                              const float* __restrict__ b2,
                                              const unsigned* __restrict__ w3p,
                                              const unsigned* __restrict__ masks,
                                              float* __restrict__ desc) {
    int p = blockIdx.x, q = blockIdx.y;
    __shared__ float h1[32];
    __shared__ __align__(16) float h2s[32];
    __shared__ int idxs[3072];
    __shared__ int cnt;
    __shared__ float wsum[4], wq[4];
    int tid = threadIdx.x;
    if (tid == 0) cnt = 0;
    __syncthreads();
    unsigned mq = masks[q * MASKW + tid];
    unsigned m = mq & masks[(NBQ + p) * MASKW + tid];
    int nb = __popc(m);
    if (nb) {
        int pos = atomicAdd(&cnt, nb);
        while (m) {
            int bit = __ffs(m) - 1;
            m &= m - 1;
            idxs[pos++] = tid * 32 + bit;
        }
    }
    if (tid < 32)
        h1[tid] = fmaxf(Cmat[q * 32 + tid] + Cmat[(NBQ + p) * 32 + tid] + b1[tid], 0.f);
    __syncthreads();
    if (tid < 32) {
        float s = b2[tid];
#pragma unroll
        for (int j = 0; j < 32; ++j) s = fmaf(w2[tid * 32 + j], h1[j], s);
        h2s[tid] = fmaxf(s, 0.f);
    }
    __syncthreads();
    int n = cnt;
    int rowi = tid >> 2, part = tid & 3;          // 64 rows/iter, 4 lanes/row
    float h2v[8];
#pragma unroll
    for (int j = 0; j < 8; ++j) h2v[j] = h2s[part * 8 + j];
    float local = 0.f;
    for (int base = 0; base < n; base += 64) {
        int r = base + rowi;
        bool act = r < n;
        float dot = 0.f;
        if (act) {
            uint4 wv = *(const uint4*)(w3p + (size_t)idxs[r] * 16 + part * 4);
            unsigned wu[4] = {wv.x, wv.y, wv.z, wv.w};
#pragma unroll
            for (int u = 0; u < 4; ++u) {
                dot += __uint_as_float(wu[u] << 16) * h2v[2 * u];
                dot += __uint_as_float(wu[u] & 0xffff0000u) * h2v[2 * u + 1];
            }
        }
        dot += __shfl_xor(dot, 1);
        dot += __shfl_xor(dot, 2);
        if (act && part == 0)
            local += 1.f + (dot >= 0.f ? dot : dot * 0.125f);
    }
    float qcf = (float)__popc(mq);
#pragma unroll
    for (int st = 1; st < 64; st <<= 1) {
        local += __shfl_xor(local, st);
        qcf   += __shfl_xor(qcf, st);
    }
    if ((tid & 63) == 0) { wsum[tid >> 6] = local; wq[tid >> 6] = qcf; }
    __syncthreads();
    if (tid == 0) {
        float t  = wsum[0] + wsum[1] + wsum[2] + wsum[3];
        float qb = wq[0] + wq[1] + wq[2] + wq[3];
        desc[q * 256 + p] = t / qb;
    }
}

// ---------------- per-q: normalize over p + geo fusion --------------------
__global__ __launch_bounds__(256) void k_final(const float* __restrict__ desc,
                                               const float* __restrict__ qloc,
                                               const float* __restrict__ ploc,
                                               const float* __restrict__ sa,
                                               const float* __restrict__ sb,
                                               const float* __restrict__ sc,
                                               const float* __restrict__ sd,
                                               float* __restrict__ out) {
    __shared__ float red[256];
    int q = blockIdx.x, tid = threadIdx.x;
    float v = desc[q * 256 + tid];
    red[tid] = v; __syncthreads();
    for (int st = 128; st > 0; st >>= 1) {
        if (tid < st) red[tid] += red[tid + st];
        __syncthreads();
    }
    float mean = red[0] * (1.f / 256.f);
    __syncthreads();
    float dv = v - mean;
    red[tid] = dv * dv; __syncthreads();
    for (int st = 128; st > 0; st >>= 1) {
        if (tid < st) red[tid] += red[tid + st];
        __syncthreads();
    }
    float var = red[0] * (1.f / 255.f);
    float norm = dv / (sqrtf(var) + 1e-6f);
    float dx = qloc[q * 2]     - ploc[tid * 2];
    float dy = qloc[q * 2 + 1] - ploc[tid * 2 + 1];
    float dist = sqrtf(dx * dx + dy * dy);
    float z = sa[0] * norm + sb[0];
    float sig = 1.f / (1.f + expf(-z));
    out[q * 256 + tid] = (sc[0] - sig) * (-logf(dist + 1.f) - sd[0]);
}

extern "C" void kernel_launch(void* const* d_in, const int* in_sizes, int n_in,
                              void* d_out, int out_size, void* d_ws, size_t ws_size,
                              hipStream_t stream) {
    const float* qx   = (const float*)d_in[0];
    const float* qloc = (const float*)d_in[1];
    const float* px   = (const float*)d_in[2];
    const float* ploc = (const float*)d_in[3];
    const float* encw = (const float*)d_in[4];
    const float* cw1  = (const float*)d_in[5];
    const float* cb1  = (const float*)d_in[6];
    const float* cw2  = (const float*)d_in[7];
    const float* cb2  = (const float*)d_in[8];
    const float* cw3  = (const float*)d_in[9];
    const float* cb3  = (const float*)d_in[10];
    const float* dw1  = (const float*)d_in[11];
    const float* db1  = (const float*)d_in[12];
    const float* dw2  = (const float*)d_in[13];
    const float* db2  = (const float*)d_in[14];
    const float* dw3  = (const float*)d_in[15];
    const float* sa   = (const float*)d_in[16];
    const float* sb   = (const float*)d_in[17];
    const float* sc   = (const float*)d_in[18];
    const float* sd   = (const float*)d_in[19];

    char* w = (char*)d_ws;
    unsigned*       wtp   = (unsigned*)w;       w += (size_t)8193 * 128 * 4;      // 4.19 MB
    unsigned short* xbuf  = (unsigned short*)w; w += (size_t)NB * LTOK * H1 * 2;  // 2.25 MB
    unsigned short* act1  = (unsigned short*)w; w += (size_t)NB * LTOK * H1 * 2;
    unsigned short* act2  = (unsigned short*)w; w += (size_t)NB * LTOK * H1 * 2;
    unsigned short* wtb   = (unsigned short*)w; w += (size_t)3 * 256 * 1280 * 2;  // 1.97 MB
    unsigned*       w3p   = (unsigned*)w;       w += (size_t)CIN * 16 * 4;        // 512 KB
    float*          esum  = (float*)w;          w += (size_t)NB * H1 * 4;         // 295 KB
    float*          Cmat  = (float*)w;          w += (size_t)NB * H2 * 4;
    unsigned*       masks = (unsigned*)w;       w += (size_t)NB * MASKW * 4;
    float*          desc  = (float*)w;          w += (size_t)NBQ * NBP * 4;

    k_prep<<<6688, 256, 0, stream>>>(encw, cw1, cw2, cw3, dw3,
                                     wtp, wtb, w3p, masks, esum, Cmat);
    k_scanG<<<NB * LTOK, 256, 0, stream>>>(qx, px, wtp, masks, esum, (unsigned*)xbuf);
    dim3 cgrid(NB * LTOK / 32, 8);
    k_cgemm<<<cgrid, 256, 0, stream>>>(xbuf, act1, wtb,          cb1);
    k_cgemm<<<cgrid, 256, 0, stream>>>(act1, act2, wtb + 327680, cb2);
    k_cgemm3<<<cgrid, 256, 0, stream>>>(act2, wtb + 2 * 327680, cb3, esum, dw1, Cmat);
    k_pair<<<dim3(NBP, NBQ), 256, 0, stream>>>(Cmat, db1, dw2, db2, w3p, masks, desc);
    k_final<<<NBQ, 256, 0, stream>>>(desc, qloc, ploc, sa, sb, sc, sd, (float*)d_out);
}